// Round 1
// baseline (12332.070 us; speedup 1.0000x reference)
//
#include <hip/hip_runtime.h>
#include <hip/hip_bf16.h>
#include <hip/hip_cooperative_groups.h>

namespace cg = cooperative_groups;

typedef __attribute__((ext_vector_type(8))) short bf16x8;
typedef __attribute__((ext_vector_type(4))) float f32x4;

constexpr int kB = 64;     // batch
constexpr int kT = 512;    // time steps
constexpr int kE = 256;    // embedding
constexpr int kH = 512;    // hidden
constexpr int kV = 32000;  // vocab
constexpr int LWGS = 64;   // workgroups per layer
constexpr int NCOL = 32;   // gate-columns per WG (8 hidden units * 4 gates)

static __device__ __forceinline__ unsigned short f2bf(float x) {
  __hip_bfloat16 h = __float2bfloat16(x);
  return __builtin_bit_cast(unsigned short, h);
}

// Pack gate weights into B-fragment layout: dst[((kc*4+g)*2048 + col)*8 + j]
//   = src_gate(col&3)[ (kc*32 + g*8 + j)*kH + (col>>2) ]
// so a lane reading 16B at ((kc*4+g)*2048+col)*8 gets B[k= kc*32+g*8+0..7][col].
__global__ void pack_w(const float* __restrict__ s0, const float* __restrict__ s1,
                       const float* __restrict__ s2, const float* __restrict__ s3,
                       unsigned short* __restrict__ dst, int K) {
  int o = blockIdx.x * 256 + threadIdx.x;
  if (o >= K * 2048) return;
  int j = o & 7;
  int col = (o >> 3) & 2047;
  int q = o >> 14;                 // kc*4 + g
  int k = (q >> 2) * 32 + (q & 3) * 8 + j;
  int hid = col >> 2;
  int gt = col & 3;
  const float* s = (gt == 0) ? s0 : (gt == 1) ? s1 : (gt == 2) ? s2 : s3;
  dst[o] = f2bf(s[(size_t)k * kH + hid]);
}

// xseq[t][b][e] = bf16(emb[X[b][t]][e])
__global__ void gather_x(const int* __restrict__ X, const float* __restrict__ emb,
                         unsigned short* __restrict__ xseq) {
  int o = blockIdx.x * 256 + threadIdx.x;   // kT*kB*(kE/8) = 1,048,576
  if (o >= kT * kB * (kE / 8)) return;
  int e8 = o & 31;
  int b  = (o >> 5) & 63;
  int t  = o >> 11;
  int tok = X[b * kT + t];
  const float* src = emb + (size_t)tok * kE + e8 * 8;
  unsigned short tmp[8];
  #pragma unroll
  for (int j = 0; j < 8; ++j) tmp[j] = f2bf(src[j]);
  unsigned short* dst = xseq + ((size_t)t * kB + b) * kE + e8 * 8;
  #pragma unroll
  for (int j = 0; j < 8; ++j) dst[j] = tmp[j];
}

// init states to ones; pack interleaved bias vectors b0cat/b1cat[j*4+gate]
__global__ void init_state(unsigned short* hbuf, float* cbuf,
                           unsigned short* h1buf, float* c1buf,
                           float* b0cat, float* b1cat,
                           const float* b_f, const float* b_i, const float* b_g,
                           const float* b_o1,
                           const float* b_f1, const float* b_i1, const float* b_g1) {
  int i = blockIdx.x * 256 + threadIdx.x;
  if (i < kB * kH) {
    hbuf[i] = 0x3F80u;  // bf16 1.0
    cbuf[i] = 1.f;
    h1buf[i] = 0x3F80u;
    c1buf[i] = 1.f;
  }
  if (i < 2048) {
    int j = i >> 2, g = i & 3;
    b0cat[i] = (g == 0) ? b_f[j]  : (g == 1) ? b_i[j]  : (g == 2) ? b_g[j]  : b_o1[j];
    b1cat[i] = (g == 0) ? b_f1[j] : (g == 1) ? b_i1[j] : (g == 2) ? b_g1[j] : b_o1[j];
  }
}

// Persistent cooperative recurrence kernel.
// WGs [0,LWGS): layer 0 step t=rnd.  WGs [LWGS,2*LWGS): layer 1 step t=rnd-1.
// Each WG owns NCOL=32 gate-columns (8 hidden units x 4 gates), weights in LDS.
__global__ void __launch_bounds__(256)
lstm_rec(const unsigned short* __restrict__ xseq,
         const unsigned short* __restrict__ U0p, const unsigned short* __restrict__ V0p,
         const unsigned short* __restrict__ U1p, const unsigned short* __restrict__ V1p,
         const float* __restrict__ b0cat, const float* __restrict__ b1cat,
         unsigned short* __restrict__ hbuf,   // [2][kB][kH] bf16 ping-pong
         float* __restrict__ cbuf,            // [kB][kH]
         unsigned short* __restrict__ hseq,   // [kT][kB][kH] bf16
         unsigned short* __restrict__ h1buf,  // [2][kB][kH]
         float* __restrict__ c1buf,
         float* __restrict__ h1f)             // [kB][kH] fp32 final h1
{
  cg::grid_group grid = cg::this_grid();
  __shared__ unsigned short smem[32768];  // 64 KB: packed weight slice

  const int tid  = threadIdx.x;
  const int lane = tid & 63;
  const int wave = tid >> 6;
  const int wg   = blockIdx.x;
  const bool isL1 = (wg >= LWGS);
  const int colbase = (isL1 ? wg - LWGS : wg) * NCOL;
  const int nkc0 = isL1 ? 16 : 8;   // K0/32 (L0: x part K=256; L1: hseq part K=512)

  // ---- stage this WG's weight slices into LDS (once) ----
  {
    const unsigned short* Wu = isL1 ? U1p : U0p;
    const unsigned short* Wv = isL1 ? V1p : V0p;
    const int nu = nkc0 * 4 * 256;
    for (int i = tid; i < nu; i += 256) {
      int m = i >> 8, r = i & 255;
      smem[i] = Wu[((size_t)m * 2048 + colbase) * 8 + r];
    }
    for (int i = tid; i < 16 * 4 * 256; i += 256) {
      int m = i >> 8, r = i & 255;
      smem[nu + i] = Wv[((size_t)m * 2048 + colbase) * 8 + r];
    }
  }
  __syncthreads();

  const int g4   = lane >> 4;
  const int l15  = lane & 15;
  const int rowA = wave * 16 + l15;        // A-operand row this lane loads
  const int rbase = wave * 16 + g4 * 4;    // C rows this lane owns
  const int lc0 = colbase + l15, lc1 = lc0 + 16;
  const int j0 = lc0 >> 2, j1 = lc1 >> 2;
  const int gate = lane & 3;
  const float* bcat = isL1 ? b1cat : b0cat;
  const float bias0 = bcat[lc0], bias1 = bcat[lc1];
  const unsigned short* smemV = smem + nkc0 * 4 * 256;
  const int K0 = nkc0 * 32;
  float* cb = isL1 ? c1buf : cbuf;

  for (int rnd = 0; rnd <= kT; ++rnd) {
    const bool active = isL1 ? (rnd >= 1) : (rnd < kT);
    if (active) {
      const int t = isL1 ? (rnd - 1) : rnd;
      const int p = t & 1;
      const unsigned short* A0 = isL1 ? (hseq + (size_t)t * kB * kH)
                                      : (xseq + (size_t)t * kB * kE);
      const unsigned short* A1 = (isL1 ? h1buf : hbuf) + (size_t)p * kB * kH;

      f32x4 acc0 = {0.f, 0.f, 0.f, 0.f};
      f32x4 acc1 = {0.f, 0.f, 0.f, 0.f};

      const unsigned short* a0p = A0 + (size_t)rowA * K0 + g4 * 8;
      #pragma unroll 4
      for (int kc = 0; kc < nkc0; ++kc) {
        bf16x8 a = *(const bf16x8*)(a0p + kc * 32);
        const unsigned short* lb = smem + (kc * 4 + g4) * 256 + l15 * 8;
        bf16x8 b0 = *(const bf16x8*)(lb);
        bf16x8 b1 = *(const bf16x8*)(lb + 128);
        acc0 = __builtin_amdgcn_mfma_f32_16x16x32_bf16(a, b0, acc0, 0, 0, 0);
        acc1 = __builtin_amdgcn_mfma_f32_16x16x32_bf16(a, b1, acc1, 0, 0, 0);
      }
      const unsigned short* a1p = A1 + (size_t)rowA * kH + g4 * 8;
      #pragma unroll 4
      for (int kc = 0; kc < 16; ++kc) {
        bf16x8 a = *(const bf16x8*)(a1p + kc * 32);
        const unsigned short* lb = smemV + (kc * 4 + g4) * 256 + l15 * 8;
        bf16x8 b0 = *(const bf16x8*)(lb);
        bf16x8 b1 = *(const bf16x8*)(lb + 128);
        acc0 = __builtin_amdgcn_mfma_f32_16x16x32_bf16(a, b0, acc0, 0, 0, 0);
        acc1 = __builtin_amdgcn_mfma_f32_16x16x32_bf16(a, b1, acc1, 0, 0, 0);
      }

      unsigned short* hout = (isL1 ? h1buf : hbuf) + (size_t)(p ^ 1) * kB * kH;
      #pragma unroll
      for (int nt = 0; nt < 2; ++nt) {
        const float bias = nt ? bias1 : bias0;
        const int jj = nt ? j1 : j0;
        #pragma unroll
        for (int r = 0; r < 4; ++r) {
          float v = (nt ? acc1[r] : acc0[r]) + bias;
          const int bl = lane & ~3;
          float vf = __shfl(v, bl);
          float vi = __shfl(v, bl | 1);
          float vg = __shfl(v, bl | 2);
          float vo = __shfl(v, bl | 3);
          float fg = 1.f / (1.f + __expf(-vf));
          float ig = 1.f / (1.f + __expf(-vi));
          float e2 = __expf(2.f * vg);
          float gg = (e2 - 1.f) / (e2 + 1.f);
          float og = 1.f / (1.f + __expf(-vo));
          int b = rbase + r;
          float cold = cb[b * kH + jj];
          float cnew = fg * cold + ig * gg;
          float e2c = __expf(2.f * cnew);
          float th = (e2c - 1.f) / (e2c + 1.f);
          float hval = og * th;
          if (gate == 0) {
            cb[b * kH + jj] = cnew;
            unsigned short hb = f2bf(hval);
            hout[b * kH + jj] = hb;
            if (!isL1) hseq[(size_t)t * kB * kH + b * kH + jj] = hb;
            else if (t == kT - 1) h1f[b * kH + jj] = hval;
          }
        }
      }
    }
    grid.sync();
  }
}

// out[b][v] = 2*sum_k h1[b][k]*Wout[k][v] + bout[v]
__global__ void head(const float* __restrict__ h1f, const float* __restrict__ Wout,
                     const float* __restrict__ bout, float* __restrict__ out) {
  __shared__ float hs[8 * kH];
  const int v = blockIdx.x * 256 + threadIdx.x;
  const int bg = blockIdx.y;  // batch group of 8
  for (int i = threadIdx.x; i < 8 * kH; i += 256)
    hs[i] = h1f[bg * 8 * kH + i];
  __syncthreads();
  float acc[8] = {0.f, 0.f, 0.f, 0.f, 0.f, 0.f, 0.f, 0.f};
  for (int k = 0; k < kH; ++k) {
    float w = Wout[(size_t)k * kV + v];
    #pragma unroll
    for (int r = 0; r < 8; ++r) acc[r] += hs[r * kH + k] * w;
  }
  float bv = bout[v];
  #pragma unroll
  for (int r = 0; r < 8; ++r)
    out[(size_t)(bg * 8 + r) * kV + v] = 2.f * acc[r] + bv;
}

extern "C" void kernel_launch(void* const* d_in, const int* in_sizes, int n_in,
                              void* d_out, int out_size, void* d_ws, size_t ws_size,
                              hipStream_t stream) {
  const int*   X     = (const int*)d_in[0];
  const float* emb   = (const float*)d_in[1];
  const float* U_f   = (const float*)d_in[2];
  const float* V_f   = (const float*)d_in[3];
  const float* b_f   = (const float*)d_in[4];
  const float* U_i   = (const float*)d_in[5];
  const float* V_i   = (const float*)d_in[6];
  const float* b_i   = (const float*)d_in[7];
  const float* U_g   = (const float*)d_in[8];
  const float* V_g   = (const float*)d_in[9];
  const float* b_g   = (const float*)d_in[10];
  const float* U_o   = (const float*)d_in[11];
  const float* U_f1  = (const float*)d_in[12];
  const float* V_f1  = (const float*)d_in[13];
  const float* b_f1  = (const float*)d_in[14];
  const float* U_i1  = (const float*)d_in[15];
  const float* V_i1  = (const float*)d_in[16];
  const float* b_i1  = (const float*)d_in[17];
  const float* U_g1  = (const float*)d_in[18];
  const float* V_g1  = (const float*)d_in[19];
  const float* b_g1  = (const float*)d_in[20];
  const float* U_o1  = (const float*)d_in[21];
  const float* V_o1  = (const float*)d_in[22];
  const float* b_o1  = (const float*)d_in[23];
  const float* W_out = (const float*)d_in[24];
  const float* b_out = (const float*)d_in[25];

  char* ws = (char*)d_ws;
  auto alloc = [&](size_t bytes) -> char* {
    char* p = ws;
    ws += (bytes + 255) & ~(size_t)255;
    return p;
  };
  unsigned short* U0p   = (unsigned short*)alloc((size_t)kE * 2048 * 2);
  unsigned short* V0p   = (unsigned short*)alloc((size_t)kH * 2048 * 2);
  unsigned short* U1p   = (unsigned short*)alloc((size_t)kH * 2048 * 2);
  unsigned short* V1p   = (unsigned short*)alloc((size_t)kH * 2048 * 2);
  unsigned short* xseq  = (unsigned short*)alloc((size_t)kT * kB * kE * 2);
  unsigned short* hseq  = (unsigned short*)alloc((size_t)kT * kB * kH * 2);
  unsigned short* hbuf  = (unsigned short*)alloc((size_t)2 * kB * kH * 2);
  unsigned short* h1buf = (unsigned short*)alloc((size_t)2 * kB * kH * 2);
  float* cbuf  = (float*)alloc((size_t)kB * kH * 4);
  float* c1buf = (float*)alloc((size_t)kB * kH * 4);
  float* h1f   = (float*)alloc((size_t)kB * kH * 4);
  float* b0cat = (float*)alloc(2048 * 4);
  float* b1cat = (float*)alloc(2048 * 4);

  // weight packing (layer0 o-gate uses V_o1! — reference quirk)
  pack_w<<<(kE * 2048 + 255) / 256, 256, 0, stream>>>(U_f, U_i, U_g, U_o, U0p, kE);
  pack_w<<<(kH * 2048 + 255) / 256, 256, 0, stream>>>(V_f, V_i, V_g, V_o1, V0p, kH);
  pack_w<<<(kH * 2048 + 255) / 256, 256, 0, stream>>>(U_f1, U_i1, U_g1, U_o1, U1p, kH);
  pack_w<<<(kH * 2048 + 255) / 256, 256, 0, stream>>>(V_f1, V_i1, V_g1, V_o1, V1p, kH);
  gather_x<<<(kT * kB * (kE / 8) + 255) / 256, 256, 0, stream>>>(X, emb, xseq);
  init_state<<<(kB * kH + 255) / 256, 256, 0, stream>>>(
      hbuf, cbuf, h1buf, c1buf, b0cat, b1cat,
      b_f, b_i, b_g, b_o1, b_f1, b_i1, b_g1);

  void* args[] = {
      (void*)&xseq, (void*)&U0p, (void*)&V0p, (void*)&U1p, (void*)&V1p,
      (void*)&b0cat, (void*)&b1cat, (void*)&hbuf, (void*)&cbuf,
      (void*)&hseq, (void*)&h1buf, (void*)&c1buf, (void*)&h1f};
  hipLaunchCooperativeKernel((const void*)lstm_rec, dim3(2 * LWGS), dim3(256),
                             args, 0, stream);

  head<<<dim3(kV / 256, 8), 256, 0, stream>>>(h1f, W_out, b_out, (float*)d_out);
}

// Round 3
// 6999.409 us; speedup vs baseline: 1.7619x; 1.7619x over previous
//
#include <hip/hip_runtime.h>
#include <hip/hip_bf16.h>

typedef __attribute__((ext_vector_type(8))) short bf16x8;
typedef __attribute__((ext_vector_type(4))) float f32x4;

constexpr int kB = 64;     // batch
constexpr int kT = 512;    // time steps
constexpr int kE = 256;    // embedding
constexpr int kH = 512;    // hidden
constexpr int kV = 32000;  // vocab
constexpr int LWGS = 64;   // workgroups per layer
constexpr int NCOL = 32;   // gate-columns per WG (8 hidden units * 4 gates)

static __device__ __forceinline__ unsigned short f2bf(float x) {
  __hip_bfloat16 h = __float2bfloat16(x);
  return __builtin_bit_cast(unsigned short, h);
}

static __device__ __forceinline__ f32x4 mfma16(bf16x8 a, bf16x8 b, f32x4 c) {
  return __builtin_amdgcn_mfma_f32_16x16x32_bf16(a, b, c, 0, 0, 0);
}

// Pack gate weights into B-fragment layout: dst[((kc*4+g)*2048 + col)*8 + j]
//   = src_gate(col&3)[ (kc*32 + g*8 + j)*kH + (col>>2) ]
__global__ void pack_w(const float* __restrict__ s0, const float* __restrict__ s1,
                       const float* __restrict__ s2, const float* __restrict__ s3,
                       unsigned short* __restrict__ dst, int K) {
  int o = blockIdx.x * 256 + threadIdx.x;
  if (o >= K * 2048) return;
  int j = o & 7;
  int col = (o >> 3) & 2047;
  int q = o >> 14;                 // kc*4 + g
  int k = (q >> 2) * 32 + (q & 3) * 8 + j;
  int hid = col >> 2;
  int gt = col & 3;
  const float* s = (gt == 0) ? s0 : (gt == 1) ? s1 : (gt == 2) ? s2 : s3;
  dst[o] = f2bf(s[(size_t)k * kH + hid]);
}

// xseq[t][b][e] = bf16(emb[X[b][t]][e])
__global__ void gather_x(const int* __restrict__ X, const float* __restrict__ emb,
                         unsigned short* __restrict__ xseq) {
  int o = blockIdx.x * 256 + threadIdx.x;   // kT*kB*(kE/8) = 1,048,576
  if (o >= kT * kB * (kE / 8)) return;
  int e8 = o & 31;
  int b  = (o >> 5) & 63;
  int t  = o >> 11;
  int tok = X[b * kT + t];
  const float* src = emb + (size_t)tok * kE + e8 * 8;
  unsigned short tmp[8];
  #pragma unroll
  for (int j = 0; j < 8; ++j) tmp[j] = f2bf(src[j]);
  unsigned short* dst = xseq + ((size_t)t * kB + b) * kE + e8 * 8;
  #pragma unroll
  for (int j = 0; j < 8; ++j) dst[j] = tmp[j];
}

// init states to ones; pack interleaved bias vectors; zero barrier slots
__global__ void init_state(unsigned short* hbuf, unsigned short* h1buf,
                           float* b0cat, float* b1cat, int* bar,
                           const float* b_f, const float* b_i, const float* b_g,
                           const float* b_o1,
                           const float* b_f1, const float* b_i1, const float* b_g1) {
  int i = blockIdx.x * 256 + threadIdx.x;
  if (i < 2 * kB * kH) {
    hbuf[i] = 0x3F80u;  // bf16 1.0
    h1buf[i] = 0x3F80u;
  }
  if (i < 2048) {
    int j = i >> 2, g = i & 3;
    b0cat[i] = (g == 0) ? b_f[j]  : (g == 1) ? b_i[j]  : (g == 2) ? b_g[j]  : b_o1[j];
    b1cat[i] = (g == 0) ? b_f1[j] : (g == 1) ? b_i1[j] : (g == 2) ? b_g1[j] : b_o1[j];
  }
  if (i < 2 * LWGS) bar[i] = 0;
}

// One LSTM layer step for this WG's 32 gate-columns.
// aU: preloaded A-fragments for the U-part (NKC0 chunks). A1: [64][512] bf16.
template <int NKC0>
__device__ __forceinline__ void layer_step(
    const bf16x8* aU, const unsigned short* __restrict__ A1,
    const unsigned short* __restrict__ smemU, const unsigned short* __restrict__ smemV,
    float bias0, float bias1, int colbase, int lane, int wave,
    float* crow, unsigned short* __restrict__ hout, float* __restrict__ h1f) {
  const int g4 = lane >> 4, l15 = lane & 15;
  const int rowA = wave * 16 + l15;
  bf16x8 aV[16];
  const unsigned short* a1p = A1 + rowA * kH + g4 * 8;
  #pragma unroll
  for (int kc = 0; kc < 16; ++kc) aV[kc] = *(const bf16x8*)(a1p + kc * 32);
  f32x4 acc0 = {0.f, 0.f, 0.f, 0.f};
  f32x4 acc1 = {0.f, 0.f, 0.f, 0.f};
  #pragma unroll
  for (int kc = 0; kc < NKC0; ++kc) {
    const unsigned short* lb = smemU + (kc * 4 + g4) * 256 + l15 * 8;
    acc0 = mfma16(aU[kc], *(const bf16x8*)lb, acc0);
    acc1 = mfma16(aU[kc], *(const bf16x8*)(lb + 128), acc1);
  }
  #pragma unroll
  for (int kc = 0; kc < 16; ++kc) {
    const unsigned short* lb = smemV + (kc * 4 + g4) * 256 + l15 * 8;
    acc0 = mfma16(aV[kc], *(const bf16x8*)lb, acc0);
    acc1 = mfma16(aV[kc], *(const bf16x8*)(lb + 128), acc1);
  }
  const int rbase = wave * 16 + g4 * 4;
  const int gate = lane & 3;
  const int bl = lane & ~3;
  #pragma unroll
  for (int nt = 0; nt < 2; ++nt) {
    const float bias = nt ? bias1 : bias0;
    const int jj = (colbase + l15 + nt * 16) >> 2;
    #pragma unroll
    for (int r = 0; r < 4; ++r) {
      float v = (nt ? acc1[r] : acc0[r]) + bias;
      float vf = __shfl(v, bl);
      float vi = __shfl(v, bl | 1);
      float vg = __shfl(v, bl | 2);
      float vo = __shfl(v, bl | 3);
      float fg = 1.f / (1.f + __expf(-vf));
      float ig = 1.f / (1.f + __expf(-vi));
      float e2 = __expf(2.f * vg);
      float gg = (e2 - 1.f) / (e2 + 1.f);
      float og = 1.f / (1.f + __expf(-vo));
      float cnew = fg * crow[nt * 4 + r] + ig * gg;
      crow[nt * 4 + r] = cnew;
      float e2c = __expf(2.f * cnew);
      float th = (e2c - 1.f) / (e2c + 1.f);
      float hval = og * th;
      if (gate == 0) {
        int b = rbase + r;
        hout[b * kH + jj] = f2bf(hval);
        if (h1f) h1f[b * kH + jj] = hval;
      }
    }
  }
}

// Persistent recurrence kernel with hand-rolled grid barrier.
// WGs [0,LWGS): layer 0 step t=rnd.  WGs [LWGS,2*LWGS): layer 1 step t=rnd-1.
__global__ void __launch_bounds__(256, 1)
lstm_rec(const unsigned short* __restrict__ xseq,
         const unsigned short* __restrict__ U0p, const unsigned short* __restrict__ V0p,
         const unsigned short* __restrict__ U1p, const unsigned short* __restrict__ V1p,
         const float* __restrict__ b0cat, const float* __restrict__ b1cat,
         unsigned short* __restrict__ hbuf,   // [2][kB][kH] bf16 ping-pong
         unsigned short* __restrict__ h1buf,  // [2][kB][kH]
         float* __restrict__ h1f,             // [kB][kH] fp32 final h1
         int* __restrict__ bar)               // [2*LWGS] round counters
{
  __shared__ unsigned short smem[32768];  // 64 KB packed weight slice

  const int tid  = threadIdx.x;
  const int lane = tid & 63;
  const int wave = tid >> 6;
  const int wg   = blockIdx.x;
  const bool isL1 = (wg >= LWGS);
  const int colbase = (isL1 ? wg - LWGS : wg) * NCOL;
  const int nkc0 = isL1 ? 16 : 8;   // U-part K/32 (L0: x K=256; L1: h K=512)

  // ---- stage this WG's weight slices into LDS (once) ----
  {
    const unsigned short* Wu = isL1 ? U1p : U0p;
    const unsigned short* Wv = isL1 ? V1p : V0p;
    const int nu = nkc0 * 1024;
    for (int i = tid; i < nu; i += 256) {
      int m = i >> 8, r = i & 255;
      smem[i] = Wu[((size_t)m * 2048 + colbase) * 8 + r];
    }
    for (int i = tid; i < 16 * 1024; i += 256) {
      int m = i >> 8, r = i & 255;
      smem[nu + i] = Wv[((size_t)m * 2048 + colbase) * 8 + r];
    }
  }
  __syncthreads();

  const unsigned short* smemV = smem + nkc0 * 1024;
  const int g4 = lane >> 4, l15 = lane & 15;
  const float* bcat = isL1 ? b1cat : b0cat;
  const float bias0 = bcat[colbase + l15];
  const float bias1 = bcat[colbase + l15 + 16];
  float crow[8] = {1.f, 1.f, 1.f, 1.f, 1.f, 1.f, 1.f, 1.f};

  bf16x8 xreg[8];  // L0: prefetched x-fragments for step t
  if (!isL1) {
    const unsigned short* xp = xseq + (size_t)(wave * 16 + l15) * kE + g4 * 8;  // t=0
    #pragma unroll
    for (int kc = 0; kc < 8; ++kc) xreg[kc] = *(const bf16x8*)(xp + kc * 32);
  }

  for (int rnd = 0; rnd <= kT; ++rnd) {
    if (isL1) {
      if (rnd >= 1) {
        const int w = rnd & 1;
        const unsigned short* A0 = hbuf + (size_t)w * kB * kH;         // h(rnd-1)
        const unsigned short* A1 = h1buf + (size_t)(w ^ 1) * kB * kH;  // h1(rnd-2)
        unsigned short* hout = h1buf + (size_t)w * kB * kH;
        bf16x8 aU[16];
        const unsigned short* a0p = A0 + (wave * 16 + l15) * kH + g4 * 8;
        #pragma unroll
        for (int kc = 0; kc < 16; ++kc) aU[kc] = *(const bf16x8*)(a0p + kc * 32);
        layer_step<16>(aU, A1, smem, smemV, bias0, bias1, colbase, lane, wave, crow,
                       hout, (rnd == kT) ? h1f : nullptr);
      }
    } else {
      if (rnd < kT) {
        const int w = rnd & 1;
        const unsigned short* A1 = hbuf + (size_t)w * kB * kH;         // h(rnd-1)
        unsigned short* hout = hbuf + (size_t)(w ^ 1) * kB * kH;
        layer_step<8>(xreg, A1, smem, smemV, bias0, bias1, colbase, lane, wave, crow,
                      hout, nullptr);
      }
    }
    if (rnd == kT) break;

    // ---- hand-rolled grid barrier ----
    __syncthreads();  // all WG threads done (drains vmcnt before s_barrier)
    if (tid == 0)
      __hip_atomic_store(bar + wg, rnd + 1, __ATOMIC_RELEASE, __HIP_MEMORY_SCOPE_AGENT);
    // overlap the spin with next-step x prefetch (xseq immutable -> safe pre-fence)
    if (!isL1 && rnd + 1 < kT) {
      const unsigned short* xp =
          xseq + ((size_t)(rnd + 1) * kB + (wave * 16 + l15)) * kE + g4 * 8;
      #pragma unroll
      for (int kc = 0; kc < 8; ++kc) xreg[kc] = *(const bf16x8*)(xp + kc * 32);
    }
    if (wave == 0) {
      const int tgt = rnd + 1;
      const int* p0 = bar + lane;
      const int* p1 = bar + 64 + lane;
      while (true) {
        int a = __hip_atomic_load(p0, __ATOMIC_RELAXED, __HIP_MEMORY_SCOPE_AGENT);
        int b = __hip_atomic_load(p1, __ATOMIC_RELAXED, __HIP_MEMORY_SCOPE_AGENT);
        if (__all(a >= tgt && b >= tgt)) break;
      }
    }
    __syncthreads();
    __builtin_amdgcn_fence(__ATOMIC_ACQUIRE, "agent");
  }
}

// out[b][v] = 2*sum_k h1[b][k]*Wout[k][v] + bout[v]
__global__ void head(const float* __restrict__ h1f, const float* __restrict__ Wout,
                     const float* __restrict__ bout, float* __restrict__ out) {
  __shared__ float hs[8 * kH];
  const int v = blockIdx.x * 256 + threadIdx.x;
  const int bg = blockIdx.y;  // batch group of 8
  for (int i = threadIdx.x; i < 8 * kH; i += 256)
    hs[i] = h1f[bg * 8 * kH + i];
  __syncthreads();
  float acc[8] = {0.f, 0.f, 0.f, 0.f, 0.f, 0.f, 0.f, 0.f};
  for (int k = 0; k < kH; ++k) {
    float w = Wout[(size_t)k * kV + v];
    #pragma unroll
    for (int r = 0; r < 8; ++r) acc[r] += hs[r * kH + k] * w;
  }
  float bv = bout[v];
  #pragma unroll
  for (int r = 0; r < 8; ++r)
    out[(size_t)(bg * 8 + r) * kV + v] = 2.f * acc[r] + bv;
}

extern "C" void kernel_launch(void* const* d_in, const int* in_sizes, int n_in,
                              void* d_out, int out_size, void* d_ws, size_t ws_size,
                              hipStream_t stream) {
  const int*   X     = (const int*)d_in[0];
  const float* emb   = (const float*)d_in[1];
  const float* U_f   = (const float*)d_in[2];
  const float* V_f   = (const float*)d_in[3];
  const float* b_f   = (const float*)d_in[4];
  const float* U_i   = (const float*)d_in[5];
  const float* V_i   = (const float*)d_in[6];
  const float* b_i   = (const float*)d_in[7];
  const float* U_g   = (const float*)d_in[8];
  const float* V_g   = (const float*)d_in[9];
  const float* b_g   = (const float*)d_in[10];
  const float* U_o   = (const float*)d_in[11];
  const float* U_f1  = (const float*)d_in[12];
  const float* V_f1  = (const float*)d_in[13];
  const float* b_f1  = (const float*)d_in[14];
  const float* U_i1  = (const float*)d_in[15];
  const float* V_i1  = (const float*)d_in[16];
  const float* b_i1  = (const float*)d_in[17];
  const float* U_g1  = (const float*)d_in[18];
  const float* V_g1  = (const float*)d_in[19];
  const float* b_g1  = (const float*)d_in[20];
  const float* U_o1  = (const float*)d_in[21];
  const float* V_o1  = (const float*)d_in[22];
  const float* b_o1  = (const float*)d_in[23];
  const float* W_out = (const float*)d_in[24];
  const float* b_out = (const float*)d_in[25];

  char* ws = (char*)d_ws;
  auto alloc = [&](size_t bytes) -> char* {
    char* p = ws;
    ws += (bytes + 255) & ~(size_t)255;
    return p;
  };
  unsigned short* U0p   = (unsigned short*)alloc((size_t)kE * 2048 * 2);
  unsigned short* V0p   = (unsigned short*)alloc((size_t)kH * 2048 * 2);
  unsigned short* U1p   = (unsigned short*)alloc((size_t)kH * 2048 * 2);
  unsigned short* V1p   = (unsigned short*)alloc((size_t)kH * 2048 * 2);
  unsigned short* xseq  = (unsigned short*)alloc((size_t)kT * kB * kE * 2);
  unsigned short* hbuf  = (unsigned short*)alloc((size_t)2 * kB * kH * 2);
  unsigned short* h1buf = (unsigned short*)alloc((size_t)2 * kB * kH * 2);
  float* h1f   = (float*)alloc((size_t)kB * kH * 4);
  float* b0cat = (float*)alloc(2048 * 4);
  float* b1cat = (float*)alloc(2048 * 4);
  int*   bar   = (int*)alloc(2 * LWGS * 4);

  // weight packing (layer0 o-gate uses V_o1 and b_o1 — reference quirk)
  pack_w<<<(kE * 2048 + 255) / 256, 256, 0, stream>>>(U_f, U_i, U_g, U_o, U0p, kE);
  pack_w<<<(kH * 2048 + 255) / 256, 256, 0, stream>>>(V_f, V_i, V_g, V_o1, V0p, kH);
  pack_w<<<(kH * 2048 + 255) / 256, 256, 0, stream>>>(U_f1, U_i1, U_g1, U_o1, U1p, kH);
  pack_w<<<(kH * 2048 + 255) / 256, 256, 0, stream>>>(V_f1, V_i1, V_g1, V_o1, V1p, kH);
  gather_x<<<(kT * kB * (kE / 8) + 255) / 256, 256, 0, stream>>>(X, emb, xseq);
  init_state<<<(2 * kB * kH + 255) / 256, 256, 0, stream>>>(
      hbuf, h1buf, b0cat, b1cat, bar,
      b_f, b_i, b_g, b_o1, b_f1, b_i1, b_g1);

  void* args[] = {
      (void*)&xseq, (void*)&U0p, (void*)&V0p, (void*)&U1p, (void*)&V1p,
      (void*)&b0cat, (void*)&b1cat, (void*)&hbuf, (void*)&h1buf,
      (void*)&h1f, (void*)&bar};
  (void)hipLaunchCooperativeKernel((const void*)lstm_rec, dim3(2 * LWGS), dim3(256),
                                   args, 0, stream);

  head<<<dim3(kV / 256, 8), 256, 0, stream>>>(h1f, W_out, b_out, (float*)d_out);
}

// Round 4
// 5718.991 us; speedup vs baseline: 2.1563x; 1.2239x over previous
//
#include <hip/hip_runtime.h>
#include <hip/hip_bf16.h>

typedef __attribute__((ext_vector_type(8))) short bf16x8;
typedef __attribute__((ext_vector_type(4))) float f32x4;

constexpr int kB = 64;     // batch
constexpr int kT = 512;    // time steps
constexpr int kE = 256;    // embedding
constexpr int kH = 512;    // hidden
constexpr int kV = 32000;  // vocab
constexpr int LWGS = 64;   // workgroups per layer
constexpr int NCOL = 32;   // gate-columns per WG (8 hidden units * 4 gates)

static __device__ __forceinline__ unsigned short f2bf(float x) {
  __hip_bfloat16 h = __float2bfloat16(x);
  return __builtin_bit_cast(unsigned short, h);
}

static __device__ __forceinline__ f32x4 mfma16(bf16x8 a, bf16x8 b, f32x4 c) {
  return __builtin_amdgcn_mfma_f32_16x16x32_bf16(a, b, c, 0, 0, 0);
}

// ---- device-scope (LLC-coherent, L2-bypass) memory ops ----
// 16x dwordx4 sc1 loads from one base (64B stride), waitcnt inside the block.
static __device__ __forceinline__ void load16_sc1(const unsigned short* p, bf16x8* a) {
  asm volatile(
      "global_load_dwordx4 %0, %16, off sc1\n\t"
      "global_load_dwordx4 %1, %16, off offset:64 sc1\n\t"
      "global_load_dwordx4 %2, %16, off offset:128 sc1\n\t"
      "global_load_dwordx4 %3, %16, off offset:192 sc1\n\t"
      "global_load_dwordx4 %4, %16, off offset:256 sc1\n\t"
      "global_load_dwordx4 %5, %16, off offset:320 sc1\n\t"
      "global_load_dwordx4 %6, %16, off offset:384 sc1\n\t"
      "global_load_dwordx4 %7, %16, off offset:448 sc1\n\t"
      "global_load_dwordx4 %8, %16, off offset:512 sc1\n\t"
      "global_load_dwordx4 %9, %16, off offset:576 sc1\n\t"
      "global_load_dwordx4 %10, %16, off offset:640 sc1\n\t"
      "global_load_dwordx4 %11, %16, off offset:704 sc1\n\t"
      "global_load_dwordx4 %12, %16, off offset:768 sc1\n\t"
      "global_load_dwordx4 %13, %16, off offset:832 sc1\n\t"
      "global_load_dwordx4 %14, %16, off offset:896 sc1\n\t"
      "global_load_dwordx4 %15, %16, off offset:960 sc1\n\t"
      "s_waitcnt vmcnt(0)"
      : "=&v"(a[0]), "=&v"(a[1]), "=&v"(a[2]), "=&v"(a[3]),
        "=&v"(a[4]), "=&v"(a[5]), "=&v"(a[6]), "=&v"(a[7]),
        "=&v"(a[8]), "=&v"(a[9]), "=&v"(a[10]), "=&v"(a[11]),
        "=&v"(a[12]), "=&v"(a[13]), "=&v"(a[14]), "=&v"(a[15])
      : "v"(p)
      : "memory");
}

// 32x dwordx4 sc1 loads from two bases (64B stride each), one waitcnt.
static __device__ __forceinline__ void load32_sc1(const unsigned short* p0,
                                                  const unsigned short* p1,
                                                  bf16x8* a) {
  asm volatile(
      "global_load_dwordx4 %0, %32, off sc1\n\t"
      "global_load_dwordx4 %1, %32, off offset:64 sc1\n\t"
      "global_load_dwordx4 %2, %32, off offset:128 sc1\n\t"
      "global_load_dwordx4 %3, %32, off offset:192 sc1\n\t"
      "global_load_dwordx4 %4, %32, off offset:256 sc1\n\t"
      "global_load_dwordx4 %5, %32, off offset:320 sc1\n\t"
      "global_load_dwordx4 %6, %32, off offset:384 sc1\n\t"
      "global_load_dwordx4 %7, %32, off offset:448 sc1\n\t"
      "global_load_dwordx4 %8, %32, off offset:512 sc1\n\t"
      "global_load_dwordx4 %9, %32, off offset:576 sc1\n\t"
      "global_load_dwordx4 %10, %32, off offset:640 sc1\n\t"
      "global_load_dwordx4 %11, %32, off offset:704 sc1\n\t"
      "global_load_dwordx4 %12, %32, off offset:768 sc1\n\t"
      "global_load_dwordx4 %13, %32, off offset:832 sc1\n\t"
      "global_load_dwordx4 %14, %32, off offset:896 sc1\n\t"
      "global_load_dwordx4 %15, %32, off offset:960 sc1\n\t"
      "global_load_dwordx4 %16, %33, off sc1\n\t"
      "global_load_dwordx4 %17, %33, off offset:64 sc1\n\t"
      "global_load_dwordx4 %18, %33, off offset:128 sc1\n\t"
      "global_load_dwordx4 %19, %33, off offset:192 sc1\n\t"
      "global_load_dwordx4 %20, %33, off offset:256 sc1\n\t"
      "global_load_dwordx4 %21, %33, off offset:320 sc1\n\t"
      "global_load_dwordx4 %22, %33, off offset:384 sc1\n\t"
      "global_load_dwordx4 %23, %33, off offset:448 sc1\n\t"
      "global_load_dwordx4 %24, %33, off offset:512 sc1\n\t"
      "global_load_dwordx4 %25, %33, off offset:576 sc1\n\t"
      "global_load_dwordx4 %26, %33, off offset:640 sc1\n\t"
      "global_load_dwordx4 %27, %33, off offset:704 sc1\n\t"
      "global_load_dwordx4 %28, %33, off offset:768 sc1\n\t"
      "global_load_dwordx4 %29, %33, off offset:832 sc1\n\t"
      "global_load_dwordx4 %30, %33, off offset:896 sc1\n\t"
      "global_load_dwordx4 %31, %33, off offset:960 sc1\n\t"
      "s_waitcnt vmcnt(0)"
      : "=&v"(a[0]), "=&v"(a[1]), "=&v"(a[2]), "=&v"(a[3]),
        "=&v"(a[4]), "=&v"(a[5]), "=&v"(a[6]), "=&v"(a[7]),
        "=&v"(a[8]), "=&v"(a[9]), "=&v"(a[10]), "=&v"(a[11]),
        "=&v"(a[12]), "=&v"(a[13]), "=&v"(a[14]), "=&v"(a[15]),
        "=&v"(a[16]), "=&v"(a[17]), "=&v"(a[18]), "=&v"(a[19]),
        "=&v"(a[20]), "=&v"(a[21]), "=&v"(a[22]), "=&v"(a[23]),
        "=&v"(a[24]), "=&v"(a[25]), "=&v"(a[26]), "=&v"(a[27]),
        "=&v"(a[28]), "=&v"(a[29]), "=&v"(a[30]), "=&v"(a[31])
      : "v"(p0), "v"(p1)
      : "memory");
}

static __device__ __forceinline__ void store_short_sc1(unsigned short* p, unsigned int v) {
  asm volatile("global_store_short %0, %1, off sc1" ::"v"(p), "v"(v) : "memory");
}

static __device__ __forceinline__ void store_int_sc1(int* p, int v) {
  asm volatile("global_store_dword %0, %1, off sc1" ::"v"(p), "v"(v) : "memory");
}

static __device__ __forceinline__ void poll2_sc1(const int* p, int& a, int& b) {
  asm volatile(
      "global_load_dword %0, %2, off sc1\n\t"
      "global_load_dword %1, %2, off offset:256 sc1\n\t"
      "s_waitcnt vmcnt(0)"
      : "=&v"(a), "=&v"(b)
      : "v"(p)
      : "memory");
}

// Pack gate weights into B-fragment layout: dst[((kc*4+g)*2048 + col)*8 + j]
//   = src_gate(col&3)[ (kc*32 + g*8 + j)*kH + (col>>2) ]
__global__ void pack_w(const float* __restrict__ s0, const float* __restrict__ s1,
                       const float* __restrict__ s2, const float* __restrict__ s3,
                       unsigned short* __restrict__ dst, int K) {
  int o = blockIdx.x * 256 + threadIdx.x;
  if (o >= K * 2048) return;
  int j = o & 7;
  int col = (o >> 3) & 2047;
  int q = o >> 14;                 // kc*4 + g
  int k = (q >> 2) * 32 + (q & 3) * 8 + j;
  int hid = col >> 2;
  int gt = col & 3;
  const float* s = (gt == 0) ? s0 : (gt == 1) ? s1 : (gt == 2) ? s2 : s3;
  dst[o] = f2bf(s[(size_t)k * kH + hid]);
}

// xseq[t][b][e] = bf16(emb[X[b][t]][e])
__global__ void gather_x(const int* __restrict__ X, const float* __restrict__ emb,
                         unsigned short* __restrict__ xseq) {
  int o = blockIdx.x * 256 + threadIdx.x;   // kT*kB*(kE/8) = 1,048,576
  if (o >= kT * kB * (kE / 8)) return;
  int e8 = o & 31;
  int b  = (o >> 5) & 63;
  int t  = o >> 11;
  int tok = X[b * kT + t];
  const float* src = emb + (size_t)tok * kE + e8 * 8;
  unsigned short tmp[8];
  #pragma unroll
  for (int j = 0; j < 8; ++j) tmp[j] = f2bf(src[j]);
  unsigned short* dst = xseq + ((size_t)t * kB + b) * kE + e8 * 8;
  #pragma unroll
  for (int j = 0; j < 8; ++j) dst[j] = tmp[j];
}

// init states to ones; pack interleaved bias vectors; zero barrier slots
__global__ void init_state(unsigned short* hbuf, unsigned short* h1buf,
                           float* b0cat, float* b1cat, int* bar,
                           const float* b_f, const float* b_i, const float* b_g,
                           const float* b_o1,
                           const float* b_f1, const float* b_i1, const float* b_g1) {
  int i = blockIdx.x * 256 + threadIdx.x;
  if (i < 2 * kB * kH) {
    hbuf[i] = 0x3F80u;  // bf16 1.0
    h1buf[i] = 0x3F80u;
  }
  if (i < 2048) {
    int j = i >> 2, g = i & 3;
    b0cat[i] = (g == 0) ? b_f[j]  : (g == 1) ? b_i[j]  : (g == 2) ? b_g[j]  : b_o1[j];
    b1cat[i] = (g == 0) ? b_f1[j] : (g == 1) ? b_i1[j] : (g == 2) ? b_g1[j] : b_o1[j];
  }
  if (i < 2 * LWGS) bar[i] = 0;
}

// MFMA + gate epilogue for this WG's 32 gate-columns, given preloaded A-fragments.
template <int NKC0>
__device__ __forceinline__ void do_step(
    const bf16x8* aU, const bf16x8* aV,
    const unsigned short* __restrict__ smemU, const unsigned short* __restrict__ smemV,
    float bias0, float bias1, int colbase, int lane, int wave,
    float* crow, unsigned short* __restrict__ hout, float* __restrict__ h1f) {
  const int g4 = lane >> 4, l15 = lane & 15;
  f32x4 acc0 = {0.f, 0.f, 0.f, 0.f};
  f32x4 acc1 = {0.f, 0.f, 0.f, 0.f};
  #pragma unroll
  for (int kc = 0; kc < NKC0; ++kc) {
    const unsigned short* lb = smemU + (kc * 4 + g4) * 256 + l15 * 8;
    acc0 = mfma16(aU[kc], *(const bf16x8*)lb, acc0);
    acc1 = mfma16(aU[kc], *(const bf16x8*)(lb + 128), acc1);
  }
  #pragma unroll
  for (int kc = 0; kc < 16; ++kc) {
    const unsigned short* lb = smemV + (kc * 4 + g4) * 256 + l15 * 8;
    acc0 = mfma16(aV[kc], *(const bf16x8*)lb, acc0);
    acc1 = mfma16(aV[kc], *(const bf16x8*)(lb + 128), acc1);
  }
  const int rbase = wave * 16 + g4 * 4;
  const int gate = lane & 3;
  const int bl = lane & ~3;
  #pragma unroll
  for (int nt = 0; nt < 2; ++nt) {
    const float bias = nt ? bias1 : bias0;
    const int jj = (colbase + l15 + nt * 16) >> 2;
    #pragma unroll
    for (int r = 0; r < 4; ++r) {
      float v = (nt ? acc1[r] : acc0[r]) + bias;
      float vf = __shfl(v, bl);
      float vi = __shfl(v, bl | 1);
      float vg = __shfl(v, bl | 2);
      float vo = __shfl(v, bl | 3);
      float fg = 1.f / (1.f + __expf(-vf));
      float ig = 1.f / (1.f + __expf(-vi));
      float e2 = __expf(2.f * vg);
      float gg = (e2 - 1.f) / (e2 + 1.f);
      float og = 1.f / (1.f + __expf(-vo));
      float cnew = fg * crow[nt * 4 + r] + ig * gg;
      crow[nt * 4 + r] = cnew;
      float e2c = __expf(2.f * cnew);
      float th = (e2c - 1.f) / (e2c + 1.f);
      float hval = og * th;
      if (gate == 0) {
        int b = rbase + r;
        store_short_sc1(hout + b * kH + jj, (unsigned int)f2bf(hval));
        if (h1f) h1f[b * kH + jj] = hval;
      }
    }
  }
}

// Persistent recurrence kernel; all cross-WG traffic is device-scope (sc1, LLC).
// WGs [0,LWGS): layer 0 step t=rnd.  WGs [LWGS,2*LWGS): layer 1 step t=rnd-1.
__global__ void __launch_bounds__(256, 1)
lstm_rec(const unsigned short* __restrict__ xseq,
         const unsigned short* __restrict__ U0p, const unsigned short* __restrict__ V0p,
         const unsigned short* __restrict__ U1p, const unsigned short* __restrict__ V1p,
         const float* __restrict__ b0cat, const float* __restrict__ b1cat,
         unsigned short* __restrict__ hbuf,   // [2][kB][kH] bf16 ping-pong
         unsigned short* __restrict__ h1buf,  // [2][kB][kH]
         float* __restrict__ h1f,             // [kB][kH] fp32 final h1
         int* __restrict__ bar)               // [2*LWGS] round counters
{
  __shared__ unsigned short smem[32768];  // 64 KB packed weight slice

  const int tid  = threadIdx.x;
  const int lane = tid & 63;
  const int wave = tid >> 6;
  const int wg   = blockIdx.x;
  const bool isL1 = (wg >= LWGS);
  const int colbase = (isL1 ? wg - LWGS : wg) * NCOL;
  const int nkc0 = isL1 ? 16 : 8;   // U-part K/32 (L0: x K=256; L1: h K=512)

  // ---- stage this WG's weight slices into LDS (once) ----
  {
    const unsigned short* Wu = isL1 ? U1p : U0p;
    const unsigned short* Wv = isL1 ? V1p : V0p;
    const int nu = nkc0 * 1024;
    for (int i = tid; i < nu; i += 256) {
      int m = i >> 8, r = i & 255;
      smem[i] = Wu[((size_t)m * 2048 + colbase) * 8 + r];
    }
    for (int i = tid; i < 16 * 1024; i += 256) {
      int m = i >> 8, r = i & 255;
      smem[nu + i] = Wv[((size_t)m * 2048 + colbase) * 8 + r];
    }
  }
  __syncthreads();

  const unsigned short* smemV = smem + nkc0 * 1024;
  const int g4 = lane >> 4, l15 = lane & 15;
  const int rowA = wave * 16 + l15;
  const float* bcat = isL1 ? b1cat : b0cat;
  const float bias0 = bcat[colbase + l15];
  const float bias1 = bcat[colbase + l15 + 16];
  float crow[8] = {1.f, 1.f, 1.f, 1.f, 1.f, 1.f, 1.f, 1.f};

  bf16x8 xreg[8];  // L0: prefetched x-fragments (plain cached loads; immutable)
  if (!isL1) {
    const unsigned short* xp = xseq + (size_t)rowA * kE + g4 * 8;  // t=0
    #pragma unroll
    for (int kc = 0; kc < 8; ++kc) xreg[kc] = *(const bf16x8*)(xp + kc * 32);
  }

  for (int rnd = 0; rnd <= kT; ++rnd) {
    if (isL1) {
      if (rnd >= 1) {
        const int w = rnd & 1;
        const unsigned short* A0 = hbuf + (size_t)w * kB * kH;         // h(rnd-1)
        const unsigned short* A1 = h1buf + (size_t)(w ^ 1) * kB * kH;  // h1(rnd-2)
        unsigned short* hout = h1buf + (size_t)w * kB * kH;
        bf16x8 aUV[32];
        load32_sc1(A0 + rowA * kH + g4 * 8, A1 + rowA * kH + g4 * 8, aUV);
        do_step<16>(aUV, aUV + 16, smem, smemV, bias0, bias1, colbase, lane, wave,
                    crow, hout, (rnd == kT) ? h1f : nullptr);
      }
    } else {
      if (rnd < kT) {
        const int w = rnd & 1;
        const unsigned short* A1 = hbuf + (size_t)w * kB * kH;         // h(rnd-1)
        unsigned short* hout = hbuf + (size_t)(w ^ 1) * kB * kH;
        bf16x8 aV[16];
        load16_sc1(A1 + rowA * kH + g4 * 8, aV);
        do_step<8>(xreg, aV, smem, smemV, bias0, bias1, colbase, lane, wave,
                   crow, hout, nullptr);
      }
    }
    if (rnd == kT) break;

    // ---- hand-rolled grid barrier (all sc1, no cache maintenance) ----
    __syncthreads();  // drains every wave's vmcnt -> h stores LLC-acked
    if (tid == 0) store_int_sc1(bar + wg, rnd + 1);
    // overlap the spin with next-step x prefetch (immutable data, cached path)
    if (!isL1 && rnd + 1 < kT) {
      const unsigned short* xp =
          xseq + ((size_t)(rnd + 1) * kB + rowA) * kE + g4 * 8;
      #pragma unroll
      for (int kc = 0; kc < 8; ++kc) xreg[kc] = *(const bf16x8*)(xp + kc * 32);
    }
    if (wave == 0) {
      const int tgt = rnd + 1;
      while (true) {
        int a, b;
        poll2_sc1(bar + lane, a, b);
        if (__all(a >= tgt && b >= tgt)) break;
      }
    }
    __syncthreads();
  }
}

// out[b][v] = 2*sum_k h1[b][k]*Wout[k][v] + bout[v]
__global__ void head(const float* __restrict__ h1f, const float* __restrict__ Wout,
                     const float* __restrict__ bout, float* __restrict__ out) {
  __shared__ float hs[8 * kH];
  const int v = blockIdx.x * 256 + threadIdx.x;
  const int bg = blockIdx.y;  // batch group of 8
  for (int i = threadIdx.x; i < 8 * kH; i += 256)
    hs[i] = h1f[bg * 8 * kH + i];
  __syncthreads();
  float acc[8] = {0.f, 0.f, 0.f, 0.f, 0.f, 0.f, 0.f, 0.f};
  for (int k = 0; k < kH; ++k) {
    float w = Wout[(size_t)k * kV + v];
    #pragma unroll
    for (int r = 0; r < 8; ++r) acc[r] += hs[r * kH + k] * w;
  }
  float bv = bout[v];
  #pragma unroll
  for (int r = 0; r < 8; ++r)
    out[(size_t)(bg * 8 + r) * kV + v] = 2.f * acc[r] + bv;
}

extern "C" void kernel_launch(void* const* d_in, const int* in_sizes, int n_in,
                              void* d_out, int out_size, void* d_ws, size_t ws_size,
                              hipStream_t stream) {
  const int*   X     = (const int*)d_in[0];
  const float* emb   = (const float*)d_in[1];
  const float* U_f   = (const float*)d_in[2];
  const float* V_f   = (const float*)d_in[3];
  const float* b_f   = (const float*)d_in[4];
  const float* U_i   = (const float*)d_in[5];
  const float* V_i   = (const float*)d_in[6];
  const float* b_i   = (const float*)d_in[7];
  const float* U_g   = (const float*)d_in[8];
  const float* V_g   = (const float*)d_in[9];
  const float* b_g   = (const float*)d_in[10];
  const float* U_o   = (const float*)d_in[11];
  const float* U_f1  = (const float*)d_in[12];
  const float* V_f1  = (const float*)d_in[13];
  const float* b_f1  = (const float*)d_in[14];
  const float* U_i1  = (const float*)d_in[15];
  const float* V_i1  = (const float*)d_in[16];
  const float* b_i1  = (const float*)d_in[17];
  const float* U_g1  = (const float*)d_in[18];
  const float* V_g1  = (const float*)d_in[19];
  const float* b_g1  = (const float*)d_in[20];
  const float* U_o1  = (const float*)d_in[21];
  const float* V_o1  = (const float*)d_in[22];
  const float* b_o1  = (const float*)d_in[23];
  const float* W_out = (const float*)d_in[24];
  const float* b_out = (const float*)d_in[25];

  char* ws = (char*)d_ws;
  auto alloc = [&](size_t bytes) -> char* {
    char* p = ws;
    ws += (bytes + 255) & ~(size_t)255;
    return p;
  };
  unsigned short* U0p   = (unsigned short*)alloc((size_t)kE * 2048 * 2);
  unsigned short* V0p   = (unsigned short*)alloc((size_t)kH * 2048 * 2);
  unsigned short* U1p   = (unsigned short*)alloc((size_t)kH * 2048 * 2);
  unsigned short* V1p   = (unsigned short*)alloc((size_t)kH * 2048 * 2);
  unsigned short* xseq  = (unsigned short*)alloc((size_t)kT * kB * kE * 2);
  unsigned short* hbuf  = (unsigned short*)alloc((size_t)2 * kB * kH * 2);
  unsigned short* h1buf = (unsigned short*)alloc((size_t)2 * kB * kH * 2);
  float* h1f   = (float*)alloc((size_t)kB * kH * 4);
  float* b0cat = (float*)alloc(2048 * 4);
  float* b1cat = (float*)alloc(2048 * 4);
  int*   bar   = (int*)alloc(2 * LWGS * 4);

  // weight packing (layer0 o-gate uses V_o1 and b_o1 — reference quirk)
  pack_w<<<(kE * 2048 + 255) / 256, 256, 0, stream>>>(U_f, U_i, U_g, U_o, U0p, kE);
  pack_w<<<(kH * 2048 + 255) / 256, 256, 0, stream>>>(V_f, V_i, V_g, V_o1, V0p, kH);
  pack_w<<<(kH * 2048 + 255) / 256, 256, 0, stream>>>(U_f1, U_i1, U_g1, U_o1, U1p, kH);
  pack_w<<<(kH * 2048 + 255) / 256, 256, 0, stream>>>(V_f1, V_i1, V_g1, V_o1, V1p, kH);
  gather_x<<<(kT * kB * (kE / 8) + 255) / 256, 256, 0, stream>>>(X, emb, xseq);
  init_state<<<(2 * kB * kH + 255) / 256, 256, 0, stream>>>(
      hbuf, h1buf, b0cat, b1cat, bar,
      b_f, b_i, b_g, b_o1, b_f1, b_i1, b_g1);

  void* args[] = {
      (void*)&xseq, (void*)&U0p, (void*)&V0p, (void*)&U1p, (void*)&V1p,
      (void*)&b0cat, (void*)&b1cat, (void*)&hbuf, (void*)&h1buf,
      (void*)&h1f, (void*)&bar};
  (void)hipLaunchCooperativeKernel((const void*)lstm_rec, dim3(2 * LWGS), dim3(256),
                                   args, 0, stream);

  head<<<dim3(kV / 256, 8), 256, 0, stream>>>(h1f, W_out, b_out, (float*)d_out);
}

// Round 5
// 3577.678 us; speedup vs baseline: 3.4469x; 1.5985x over previous
//
#include <hip/hip_runtime.h>
#include <hip/hip_bf16.h>

typedef __attribute__((ext_vector_type(8))) short bf16x8;
typedef __attribute__((ext_vector_type(4))) float f32x4;
typedef __attribute__((ext_vector_type(2))) int int32x2;
typedef __attribute__((ext_vector_type(4))) int int32x4;

constexpr int kB = 64;      // batch
constexpr int kT = 512;     // time steps
constexpr int kE = 256;     // embedding
constexpr int kH = 512;     // hidden
constexpr int kV = 32000;   // vocab
constexpr int kBH = kB * kH;

static __device__ __forceinline__ unsigned short f2bf(float x) {
  __hip_bfloat16 h = __float2bfloat16(x);
  return __builtin_bit_cast(unsigned short, h);
}

static __device__ __forceinline__ f32x4 mfma16(bf16x8 a, bf16x8 b, f32x4 c) {
  return __builtin_amdgcn_mfma_f32_16x16x32_bf16(a, b, c, 0, 0, 0);
}

// issue 16 dwordx4 sc1 loads (64B stride), NO wait — overlap with compute.
static __device__ __forceinline__ void issue16_sc1(const unsigned short* p, bf16x8* a) {
  asm volatile(
      "global_load_dwordx4 %0, %16, off sc1\n\t"
      "global_load_dwordx4 %1, %16, off offset:64 sc1\n\t"
      "global_load_dwordx4 %2, %16, off offset:128 sc1\n\t"
      "global_load_dwordx4 %3, %16, off offset:192 sc1\n\t"
      "global_load_dwordx4 %4, %16, off offset:256 sc1\n\t"
      "global_load_dwordx4 %5, %16, off offset:320 sc1\n\t"
      "global_load_dwordx4 %6, %16, off offset:384 sc1\n\t"
      "global_load_dwordx4 %7, %16, off offset:448 sc1\n\t"
      "global_load_dwordx4 %8, %16, off offset:512 sc1\n\t"
      "global_load_dwordx4 %9, %16, off offset:576 sc1\n\t"
      "global_load_dwordx4 %10, %16, off offset:640 sc1\n\t"
      "global_load_dwordx4 %11, %16, off offset:704 sc1\n\t"
      "global_load_dwordx4 %12, %16, off offset:768 sc1\n\t"
      "global_load_dwordx4 %13, %16, off offset:832 sc1\n\t"
      "global_load_dwordx4 %14, %16, off offset:896 sc1\n\t"
      "global_load_dwordx4 %15, %16, off offset:960 sc1"
      : "=&v"(a[0]), "=&v"(a[1]), "=&v"(a[2]), "=&v"(a[3]),
        "=&v"(a[4]), "=&v"(a[5]), "=&v"(a[6]), "=&v"(a[7]),
        "=&v"(a[8]), "=&v"(a[9]), "=&v"(a[10]), "=&v"(a[11]),
        "=&v"(a[12]), "=&v"(a[13]), "=&v"(a[14]), "=&v"(a[15])
      : "v"(p));
}

// vmcnt(0) with the 16 fragments tied: consumers get a data-dep on this asm,
// so the compiler cannot hoist MFMAs above the wait (rule #18 safe).
static __device__ __forceinline__ void wait_frags16(bf16x8* a) {
  asm volatile("s_waitcnt vmcnt(0)"
               : "+v"(a[0]), "+v"(a[1]), "+v"(a[2]), "+v"(a[3]),
                 "+v"(a[4]), "+v"(a[5]), "+v"(a[6]), "+v"(a[7]),
                 "+v"(a[8]), "+v"(a[9]), "+v"(a[10]), "+v"(a[11]),
                 "+v"(a[12]), "+v"(a[13]), "+v"(a[14]), "+v"(a[15])
               :
               : "memory");
}

static __device__ __forceinline__ void store_dwordx2_sc1(unsigned short* p, int32x2 v) {
  asm volatile("global_store_dwordx2 %0, %1, off sc1" ::"v"(p), "v"(v) : "memory");
}

static __device__ __forceinline__ void store_int_sc1(int* p, int v) {
  asm volatile("global_store_dword %0, %1, off sc1" ::"v"(p), "v"(v) : "memory");
}

static __device__ __forceinline__ void poll_all(const int* bar, int lane, int tgt) {
  const int* p = bar + lane * 4;
  while (true) {
    int32x4 v;
    asm volatile("global_load_dwordx4 %0, %1, off sc1\n\ts_waitcnt vmcnt(0)"
                 : "=&v"(v)
                 : "v"(p)
                 : "memory");
    if (__all(v.x >= tgt && v.y >= tgt && v.z >= tgt && v.w >= tgt)) break;
  }
}

// Pack weights into A-fragment slices: P[hb][kc][gate][lane][j]
//   = src_gate[(kc*32 + (lane>>4)*8 + j) * kH + hb*16 + (lane&15)]
__global__ void pack_w(const float* __restrict__ s0, const float* __restrict__ s1,
                       const float* __restrict__ s2, const float* __restrict__ s3,
                       unsigned short* __restrict__ dst, int K) {
  int o = blockIdx.x * 256 + threadIdx.x;
  if (o >= K * 2048) return;
  int j = o & 7;
  int lane = (o >> 3) & 63;
  int gate = (o >> 9) & 3;
  int r2 = o >> 11;
  int kc = r2 % (K / 32);
  int hb = r2 / (K / 32);
  int k = kc * 32 + (lane >> 4) * 8 + j;
  int hid = hb * 16 + (lane & 15);
  const float* s = (gate == 0) ? s0 : (gate == 1) ? s1 : (gate == 2) ? s2 : s3;
  dst[o] = f2bf(s[(size_t)k * kH + hid]);
}

// xseq[t][b][e] = bf16(emb[X[b][t]][e])
__global__ void gather_x(const int* __restrict__ X, const float* __restrict__ emb,
                         unsigned short* __restrict__ xseq) {
  int o = blockIdx.x * 256 + threadIdx.x;
  if (o >= kT * kB * (kE / 8)) return;
  int e8 = o & 31;
  int b = (o >> 5) & 63;
  int t = o >> 11;
  int tok = X[b * kT + t];
  const float* src = emb + (size_t)tok * kE + e8 * 8;
  unsigned short tmp[8];
#pragma unroll
  for (int j = 0; j < 8; ++j) tmp[j] = f2bf(src[j]);
  unsigned short* dst = xseq + ((size_t)t * kB + b) * kE + e8 * 8;
#pragma unroll
  for (int j = 0; j < 8; ++j) dst[j] = tmp[j];
}

// init states to ones; planar bias arrays [4][512]; zero flags
__global__ void init_state(unsigned short* hbuf, unsigned short* h1buf,
                           float* bcat0, float* bcat1, int* bar,
                           const float* b_f, const float* b_i, const float* b_g,
                           const float* b_o1,
                           const float* b_f1, const float* b_i1, const float* b_g1) {
  int i = blockIdx.x * 256 + threadIdx.x;
  if (i < 4 * kBH) hbuf[i] = 0x3F80u;  // bf16 1.0
  if (i < 2 * kBH) h1buf[i] = 0x3F80u;
  if (i < 512) {
    bcat0[i] = b_f[i];  bcat0[512 + i] = b_i[i];
    bcat0[1024 + i] = b_g[i];  bcat0[1536 + i] = b_o1[i];
    bcat1[i] = b_f1[i]; bcat1[512 + i] = b_i1[i];
    bcat1[1024 + i] = b_g1[i]; bcat1[1536 + i] = b_o1[i];
  }
  if (i < 256) bar[i] = 0;
}

// Persistent recurrence: 256 WGs x 64 threads (1 wave each, 1 per CU).
// WGs [0,128): layer0, step t=rnd.  WGs [128,256): layer1, step t=rnd-2 (lag 2).
// Each WG: 16 hidden units (hb) x 16 batches (bt). All cross-WG traffic sc1.
__global__ void __launch_bounds__(64, 1)
lstm_rec(const unsigned short* __restrict__ xseq,
         const unsigned short* __restrict__ U0p, const unsigned short* __restrict__ V0p,
         const unsigned short* __restrict__ U1p, const unsigned short* __restrict__ V1p,
         const float* __restrict__ bcat0, const float* __restrict__ bcat1,
         unsigned short* __restrict__ hbuf,   // [4][64][512] bf16
         unsigned short* __restrict__ h1buf,  // [2][64][512] bf16
         float* __restrict__ h1f,             // [64][512] fp32 final h1
         int* __restrict__ bar)               // [256] per-WG round flags
{
  extern __shared__ unsigned short lds[];
  const int lane = threadIdx.x;
  const int wg = blockIdx.x;
  const bool isL1 = wg >= 128;
  const int wl = isL1 ? wg - 128 : wg;
  const int hb = wl >> 2, bt = wl & 3;
  const int l15 = lane & 15, g4 = lane >> 4;
  const int batch = bt * 16 + l15;
  const int hid4 = hb * 16 + g4 * 4;
  const int KU = isL1 ? 512 : 256;

  // stage this WG's weight slice (A-fragment layout) into LDS, once
  {
    const unsigned short* Wu = isL1 ? U1p : U0p;
    const unsigned short* Wv = isL1 ? V1p : V0p;
    const int nu = KU * 64, nv = 512 * 64;
    const bf16x8* su = (const bf16x8*)(Wu + (size_t)hb * nu);
    bf16x8* d = (bf16x8*)lds;
    for (int i = lane; i < nu / 8; i += 64) d[i] = su[i];
    const bf16x8* sv = (const bf16x8*)(Wv + (size_t)hb * nv);
    bf16x8* d2 = (bf16x8*)(lds + nu);
    for (int i = lane; i < nv / 8; i += 64) d2[i] = sv[i];
  }
  // single wave: ds_write->ds_read ordering handled by compiler lgkmcnt

  const float* bc = isL1 ? bcat1 : bcat0;
  const float4 bF = *(const float4*)(bc + 0 * 512 + hid4);
  const float4 bI = *(const float4*)(bc + 1 * 512 + hid4);
  const float4 bG = *(const float4*)(bc + 2 * 512 + hid4);
  const float4 bO = *(const float4*)(bc + 3 * 512 + hid4);
  float cst[4] = {1.f, 1.f, 1.f, 1.f};

#define GATE_EPILOGUE(hv)                                                      \
  float hv[4];                                                                 \
  {                                                                            \
    const float bfv[4] = {bF.x, bF.y, bF.z, bF.w};                             \
    const float biv[4] = {bI.x, bI.y, bI.z, bI.w};                             \
    const float bgv[4] = {bG.x, bG.y, bG.z, bG.w};                             \
    const float bov[4] = {bO.x, bO.y, bO.z, bO.w};                             \
    _Pragma("unroll") for (int r = 0; r < 4; ++r) {                            \
      float fg = 1.f / (1.f + __expf(-(acc[0][r] + bfv[r])));                  \
      float ig = 1.f / (1.f + __expf(-(acc[1][r] + biv[r])));                  \
      float e2 = __expf(2.f * (acc[2][r] + bgv[r]));                           \
      float gg = (e2 - 1.f) / (e2 + 1.f);                                      \
      float og = 1.f / (1.f + __expf(-(acc[3][r] + bov[r])));                  \
      float cn = fg * cst[r] + ig * gg;                                        \
      cst[r] = cn;                                                             \
      float e2c = __expf(2.f * cn);                                            \
      hv[r] = og * (e2c - 1.f) / (e2c + 1.f);                                  \
    }                                                                          \
  }

  if (!isL1) {
    // ---------------- layer 0: t = rnd ----------------
    bf16x8 xr[8];
    {
      const unsigned short* xp = xseq + (size_t)batch * kE + g4 * 8;  // t=0
#pragma unroll
      for (int kc = 0; kc < 8; ++kc) xr[kc] = *(const bf16x8*)(xp + kc * 32);
    }
    for (int rnd = 0;; ++rnd) {
      if (rnd < kT) {
        bf16x8 vF[16];
        issue16_sc1(hbuf + (size_t)((rnd - 1) & 3) * kBH + batch * kH + g4 * 8, vF);
        f32x4 acc[4] = {{0, 0, 0, 0}, {0, 0, 0, 0}, {0, 0, 0, 0}, {0, 0, 0, 0}};
#pragma unroll
        for (int kc = 0; kc < 8; ++kc) {  // U-part (x) on prefetched frags
          const unsigned short* ab = lds + kc * 2048 + lane * 8;
          acc[0] = mfma16(*(const bf16x8*)ab, xr[kc], acc[0]);
          acc[1] = mfma16(*(const bf16x8*)(ab + 512), xr[kc], acc[1]);
          acc[2] = mfma16(*(const bf16x8*)(ab + 1024), xr[kc], acc[2]);
          acc[3] = mfma16(*(const bf16x8*)(ab + 1536), xr[kc], acc[3]);
        }
        wait_frags16(vF);
#pragma unroll
        for (int kc = 0; kc < 16; ++kc) {  // V-part (h recurrent)
          const unsigned short* ab = lds + (8 + kc) * 2048 + lane * 8;
          acc[0] = mfma16(*(const bf16x8*)ab, vF[kc], acc[0]);
          acc[1] = mfma16(*(const bf16x8*)(ab + 512), vF[kc], acc[1]);
          acc[2] = mfma16(*(const bf16x8*)(ab + 1024), vF[kc], acc[2]);
          acc[3] = mfma16(*(const bf16x8*)(ab + 1536), vF[kc], acc[3]);
        }
        GATE_EPILOGUE(hv)
        unsigned int lo = (unsigned)f2bf(hv[0]) | ((unsigned)f2bf(hv[1]) << 16);
        unsigned int hi = (unsigned)f2bf(hv[2]) | ((unsigned)f2bf(hv[3]) << 16);
        int32x2 pk = {(int)lo, (int)hi};
        store_dwordx2_sc1(hbuf + (size_t)(rnd & 3) * kBH + batch * kH + hid4, pk);
      }
      if (rnd + 1 < kT) {  // prefetch next x (immutable, cached path)
        const unsigned short* xp =
            xseq + ((size_t)(rnd + 1) * kB + batch) * kE + g4 * 8;
#pragma unroll
        for (int kc = 0; kc < 8; ++kc) xr[kc] = *(const bf16x8*)(xp + kc * 32);
      }
      if (rnd == kT + 1) break;
      asm volatile("s_waitcnt vmcnt(0)" ::: "memory");  // h-store acked
      if (lane == 0) store_int_sc1(bar + wg, rnd + 1);
      poll_all(bar, lane, rnd + 1);
    }
  } else {
    // ---------------- layer 1: t = rnd - 2 ----------------
    bf16x8 uF[16];
#pragma unroll
    for (int i = 0; i < 16; ++i) uF[i] = (bf16x8)(short)0;
    for (int rnd = 0;; ++rnd) {
      if (rnd >= 2) {
        const int t = rnd - 2;
        bf16x8 vF[16];
        issue16_sc1(h1buf + (size_t)((rnd - 1) & 1) * kBH + batch * kH + g4 * 8, vF);
        f32x4 acc[4] = {{0, 0, 0, 0}, {0, 0, 0, 0}, {0, 0, 0, 0}, {0, 0, 0, 0}};
#pragma unroll
        for (int kc = 0; kc < 16; ++kc) {  // U-part (h(t), prefetched last round)
          const unsigned short* ab = lds + kc * 2048 + lane * 8;
          acc[0] = mfma16(*(const bf16x8*)ab, uF[kc], acc[0]);
          acc[1] = mfma16(*(const bf16x8*)(ab + 512), uF[kc], acc[1]);
          acc[2] = mfma16(*(const bf16x8*)(ab + 1024), uF[kc], acc[2]);
          acc[3] = mfma16(*(const bf16x8*)(ab + 1536), uF[kc], acc[3]);
        }
        wait_frags16(vF);
#pragma unroll
        for (int kc = 0; kc < 16; ++kc) {  // V-part (h1 recurrent)
          const unsigned short* ab = lds + (16 + kc) * 2048 + lane * 8;
          acc[0] = mfma16(*(const bf16x8*)ab, vF[kc], acc[0]);
          acc[1] = mfma16(*(const bf16x8*)(ab + 512), vF[kc], acc[1]);
          acc[2] = mfma16(*(const bf16x8*)(ab + 1024), vF[kc], acc[2]);
          acc[3] = mfma16(*(const bf16x8*)(ab + 1536), vF[kc], acc[3]);
        }
        GATE_EPILOGUE(hv)
        if (t == kT - 1) {
          f32x4 hq = {hv[0], hv[1], hv[2], hv[3]};
          *(f32x4*)(h1f + (size_t)batch * kH + hid4) = hq;  // plain; kernel-end flush
        } else {
          unsigned int lo = (unsigned)f2bf(hv[0]) | ((unsigned)f2bf(hv[1]) << 16);
          unsigned int hi = (unsigned)f2bf(hv[2]) | ((unsigned)f2bf(hv[3]) << 16);
          int32x2 pk = {(int)lo, (int)hi};
          store_dwordx2_sc1(h1buf + (size_t)(rnd & 1) * kBH + batch * kH + hid4, pk);
        }
      }
      // prefetch h(rnd-1) = next round's U-operand (stable since round rnd-1 end)
      if (rnd >= 1 && rnd <= kT)
        issue16_sc1(hbuf + (size_t)((rnd - 1) & 3) * kBH + batch * kH + g4 * 8, uF);
      if (rnd == kT + 1) break;
      wait_frags16(uF);  // vmcnt(0): store acked + prefetch complete
      if (lane == 0) store_int_sc1(bar + wg, rnd + 1);
      poll_all(bar, lane, rnd + 1);
    }
  }
#undef GATE_EPILOGUE
}

// out[b][v] = 2*sum_k h1[b][k]*Wout[k][v] + bout[v]; 32 batches per block
__global__ void head(const float* __restrict__ h1f, const float* __restrict__ Wout,
                     const float* __restrict__ bout, float* __restrict__ out) {
  extern __shared__ float hs[];  // [32][512]
  const int v = blockIdx.x * 256 + threadIdx.x;
  const int half = blockIdx.y;
  for (int i = threadIdx.x; i < 32 * kH; i += 256) hs[i] = h1f[half * 32 * kH + i];
  __syncthreads();
  float acc[32];
#pragma unroll
  for (int r = 0; r < 32; ++r) acc[r] = 0.f;
  for (int k = 0; k < kH; k += 4) {
    float w0 = Wout[(size_t)k * kV + v];
    float w1 = Wout[(size_t)(k + 1) * kV + v];
    float w2 = Wout[(size_t)(k + 2) * kV + v];
    float w3 = Wout[(size_t)(k + 3) * kV + v];
#pragma unroll
    for (int r = 0; r < 32; ++r) {
      float4 h4 = *(const float4*)&hs[r * kH + k];
      acc[r] += h4.x * w0 + h4.y * w1 + h4.z * w2 + h4.w * w3;
    }
  }
  float bv = bout[v];
#pragma unroll
  for (int r = 0; r < 32; ++r)
    out[(size_t)(half * 32 + r) * kV + v] = 2.f * acc[r] + bv;
}

extern "C" void kernel_launch(void* const* d_in, const int* in_sizes, int n_in,
                              void* d_out, int out_size, void* d_ws, size_t ws_size,
                              hipStream_t stream) {
  const int*   X     = (const int*)d_in[0];
  const float* emb   = (const float*)d_in[1];
  const float* U_f   = (const float*)d_in[2];
  const float* V_f   = (const float*)d_in[3];
  const float* b_f   = (const float*)d_in[4];
  const float* U_i   = (const float*)d_in[5];
  const float* V_i   = (const float*)d_in[6];
  const float* b_i   = (const float*)d_in[7];
  const float* U_g   = (const float*)d_in[8];
  const float* V_g   = (const float*)d_in[9];
  const float* b_g   = (const float*)d_in[10];
  const float* U_o   = (const float*)d_in[11];
  const float* U_f1  = (const float*)d_in[12];
  const float* V_f1  = (const float*)d_in[13];
  const float* b_f1  = (const float*)d_in[14];
  const float* U_i1  = (const float*)d_in[15];
  const float* V_i1  = (const float*)d_in[16];
  const float* b_i1  = (const float*)d_in[17];
  const float* U_g1  = (const float*)d_in[18];
  const float* V_g1  = (const float*)d_in[19];
  const float* b_g1  = (const float*)d_in[20];
  const float* U_o1  = (const float*)d_in[21];
  const float* V_o1  = (const float*)d_in[22];
  const float* b_o1  = (const float*)d_in[23];
  const float* W_out = (const float*)d_in[24];
  const float* b_out = (const float*)d_in[25];

  char* ws = (char*)d_ws;
  auto alloc = [&](size_t bytes) -> char* {
    char* p = ws;
    ws += (bytes + 255) & ~(size_t)255;
    return p;
  };
  unsigned short* U0p   = (unsigned short*)alloc((size_t)kE * 2048 * 2);
  unsigned short* V0p   = (unsigned short*)alloc((size_t)kH * 2048 * 2);
  unsigned short* U1p   = (unsigned short*)alloc((size_t)kH * 2048 * 2);
  unsigned short* V1p   = (unsigned short*)alloc((size_t)kH * 2048 * 2);
  unsigned short* xseq  = (unsigned short*)alloc((size_t)kT * kB * kE * 2);
  unsigned short* hbuf  = (unsigned short*)alloc((size_t)4 * kBH * 2);
  unsigned short* h1buf = (unsigned short*)alloc((size_t)2 * kBH * 2);
  float* h1f   = (float*)alloc((size_t)kBH * 4);
  float* bcat0 = (float*)alloc(4 * 512 * 4);
  float* bcat1 = (float*)alloc(4 * 512 * 4);
  int*   bar   = (int*)alloc(256 * 4);

  // weight packing (layer0 o-gate uses V_o1 and b_o1 — reference quirk)
  pack_w<<<(kE * 2048 + 255) / 256, 256, 0, stream>>>(U_f, U_i, U_g, U_o, U0p, kE);
  pack_w<<<(kH * 2048 + 255) / 256, 256, 0, stream>>>(V_f, V_i, V_g, V_o1, V0p, kH);
  pack_w<<<(kH * 2048 + 255) / 256, 256, 0, stream>>>(U_f1, U_i1, U_g1, U_o1, U1p, kH);
  pack_w<<<(kH * 2048 + 255) / 256, 256, 0, stream>>>(V_f1, V_i1, V_g1, V_o1, V1p, kH);
  gather_x<<<(kT * kB * (kE / 8) + 255) / 256, 256, 0, stream>>>(X, emb, xseq);
  init_state<<<(4 * kBH + 255) / 256, 256, 0, stream>>>(
      hbuf, h1buf, bcat0, bcat1, bar,
      b_f, b_i, b_g, b_o1, b_f1, b_i1, b_g1);

  (void)hipFuncSetAttribute((const void*)lstm_rec,
                            hipFuncAttributeMaxDynamicSharedMemorySize, 131072);
  void* args[] = {
      (void*)&xseq, (void*)&U0p, (void*)&V0p, (void*)&U1p, (void*)&V1p,
      (void*)&bcat0, (void*)&bcat1, (void*)&hbuf, (void*)&h1buf,
      (void*)&h1f, (void*)&bar};
  (void)hipLaunchCooperativeKernel((const void*)lstm_rec, dim3(256), dim3(64),
                                   args, 131072, stream);

  head<<<dim3(kV / 256, 2), 256, 65536, stream>>>(h1f, W_out, b_out, (float*)d_out);
}

// Round 6
// 2644.762 us; speedup vs baseline: 4.6628x; 1.3527x over previous
//
#include <hip/hip_runtime.h>
#include <hip/hip_bf16.h>

typedef __attribute__((ext_vector_type(8))) short bf16x8;
typedef __attribute__((ext_vector_type(4))) float f32x4;
typedef __attribute__((ext_vector_type(2))) int int32x2;

constexpr int kB = 64;      // batch
constexpr int kT = 512;     // time steps
constexpr int kE = 256;     // embedding
constexpr int kH = 512;     // hidden
constexpr int kV = 32000;   // vocab
constexpr int kBH = kB * kH;
constexpr int FSTR = 16;    // flag stride (ints) = 64B padding

static __device__ __forceinline__ unsigned short f2bf(float x) {
  __hip_bfloat16 h = __float2bfloat16(x);
  return __builtin_bit_cast(unsigned short, h);
}

static __device__ __forceinline__ f32x4 mfma16(bf16x8 a, bf16x8 b, f32x4 c) {
  return __builtin_amdgcn_mfma_f32_16x16x32_bf16(a, b, c, 0, 0, 0);
}

// issue 16 dwordx4 sc1 loads (64B stride), NO wait — overlap with compute.
static __device__ __forceinline__ void issue16_sc1(const unsigned short* p, bf16x8* a) {
  asm volatile(
      "global_load_dwordx4 %0, %16, off sc1\n\t"
      "global_load_dwordx4 %1, %16, off offset:64 sc1\n\t"
      "global_load_dwordx4 %2, %16, off offset:128 sc1\n\t"
      "global_load_dwordx4 %3, %16, off offset:192 sc1\n\t"
      "global_load_dwordx4 %4, %16, off offset:256 sc1\n\t"
      "global_load_dwordx4 %5, %16, off offset:320 sc1\n\t"
      "global_load_dwordx4 %6, %16, off offset:384 sc1\n\t"
      "global_load_dwordx4 %7, %16, off offset:448 sc1\n\t"
      "global_load_dwordx4 %8, %16, off offset:512 sc1\n\t"
      "global_load_dwordx4 %9, %16, off offset:576 sc1\n\t"
      "global_load_dwordx4 %10, %16, off offset:640 sc1\n\t"
      "global_load_dwordx4 %11, %16, off offset:704 sc1\n\t"
      "global_load_dwordx4 %12, %16, off offset:768 sc1\n\t"
      "global_load_dwordx4 %13, %16, off offset:832 sc1\n\t"
      "global_load_dwordx4 %14, %16, off offset:896 sc1\n\t"
      "global_load_dwordx4 %15, %16, off offset:960 sc1"
      : "=&v"(a[0]), "=&v"(a[1]), "=&v"(a[2]), "=&v"(a[3]),
        "=&v"(a[4]), "=&v"(a[5]), "=&v"(a[6]), "=&v"(a[7]),
        "=&v"(a[8]), "=&v"(a[9]), "=&v"(a[10]), "=&v"(a[11]),
        "=&v"(a[12]), "=&v"(a[13]), "=&v"(a[14]), "=&v"(a[15])
      : "v"(p));
}

// vmcnt(0) with the 16 fragments tied: consumers get a data-dep on this asm,
// so the compiler cannot hoist MFMAs above the wait (rule #18 safe).
static __device__ __forceinline__ void wait_frags16(bf16x8* a) {
  asm volatile("s_waitcnt vmcnt(0)"
               : "+v"(a[0]), "+v"(a[1]), "+v"(a[2]), "+v"(a[3]),
                 "+v"(a[4]), "+v"(a[5]), "+v"(a[6]), "+v"(a[7]),
                 "+v"(a[8]), "+v"(a[9]), "+v"(a[10]), "+v"(a[11]),
                 "+v"(a[12]), "+v"(a[13]), "+v"(a[14]), "+v"(a[15])
               :
               : "memory");
}

static __device__ __forceinline__ void store_dwordx2_sc1(unsigned short* p, int32x2 v) {
  asm volatile("global_store_dwordx2 %0, %1, off sc1" ::"v"(p), "v"(v) : "memory");
}

static __device__ __forceinline__ void store_int_sc1(int* p, int v) {
  asm volatile("global_store_dword %0, %1, off sc1" ::"v"(p), "v"(v) : "memory");
}

// spin until (per-lane) *p >= thr for all 64 lanes; 1 dword sc1 load/lane/iter.
static __device__ __forceinline__ void pollgate(const int* p, int thr) {
  while (true) {
    int v;
    asm volatile("global_load_dword %0, %1, off sc1\n\ts_waitcnt vmcnt(0)"
                 : "=&v"(v)
                 : "v"(p)
                 : "memory");
    if (__all(v >= thr)) break;
  }
}

// Pack weights into A-fragment slices: P[hb][kc][gate][lane][j]
//   = src_gate[(kc*32 + (lane>>4)*8 + j) * kH + hb*16 + (lane&15)]
__global__ void pack_w(const float* __restrict__ s0, const float* __restrict__ s1,
                       const float* __restrict__ s2, const float* __restrict__ s3,
                       unsigned short* __restrict__ dst, int K) {
  int o = blockIdx.x * 256 + threadIdx.x;
  if (o >= K * 2048) return;
  int j = o & 7;
  int lane = (o >> 3) & 63;
  int gate = (o >> 9) & 3;
  int r2 = o >> 11;
  int kc = r2 % (K / 32);
  int hb = r2 / (K / 32);
  int k = kc * 32 + (lane >> 4) * 8 + j;
  int hid = hb * 16 + (lane & 15);
  const float* s = (gate == 0) ? s0 : (gate == 1) ? s1 : (gate == 2) ? s2 : s3;
  dst[o] = f2bf(s[(size_t)k * kH + hid]);
}

// xseq[t][b][e] = bf16(emb[X[b][t]][e])
__global__ void gather_x(const int* __restrict__ X, const float* __restrict__ emb,
                         unsigned short* __restrict__ xseq) {
  int o = blockIdx.x * 256 + threadIdx.x;
  if (o >= kT * kB * (kE / 8)) return;
  int e8 = o & 31;
  int b = (o >> 5) & 63;
  int t = o >> 11;
  int tok = X[b * kT + t];
  const float* src = emb + (size_t)tok * kE + e8 * 8;
  unsigned short tmp[8];
#pragma unroll
  for (int j = 0; j < 8; ++j) tmp[j] = f2bf(src[j]);
  unsigned short* dst = xseq + ((size_t)t * kB + b) * kE + e8 * 8;
#pragma unroll
  for (int j = 0; j < 8; ++j) dst[j] = tmp[j];
}

// init states to ones; planar bias arrays [4][512]; zero flags
__global__ void init_state(unsigned short* hbuf, unsigned short* h1buf,
                           float* bcat0, float* bcat1, int* fl0, int* fl1,
                           const float* b_f, const float* b_i, const float* b_g,
                           const float* b_o1,
                           const float* b_f1, const float* b_i1, const float* b_g1) {
  int i = blockIdx.x * 256 + threadIdx.x;
  if (i < 8 * kBH) hbuf[i] = 0x3F80u;  // bf16 1.0
  if (i < 2 * kBH) h1buf[i] = 0x3F80u;
  if (i < 512) {
    bcat0[i] = b_f[i];  bcat0[512 + i] = b_i[i];
    bcat0[1024 + i] = b_g[i];  bcat0[1536 + i] = b_o1[i];
    bcat1[i] = b_f1[i]; bcat1[512 + i] = b_i1[i];
    bcat1[1024 + i] = b_g1[i]; bcat1[1536 + i] = b_o1[i];
  }
  if (i < 4 * 32 * FSTR) { fl0[i] = 0; fl1[i] = 0; }
}

// Persistent recurrence: 256 WGs x 64 threads (1 wave each, 1 per CU).
// WGs [0,128): layer0 (h).  WGs [128,256): layer1 (h1).
// wl = wg&127; hb = wl>>2 (hidden block), bt = wl&3 (batch group of 16).
// No global barrier: point-to-point flags along true dependencies, per bt-group.
//   L0 step t: needs flagsL0[bt][*] >= t      (vF = h(t-1))
//              and  flagsL1[bt][*] >= t-7     (slot t&7 reuse, 8-deep hbuf)
//   L1 step s: needs flagsL0[bt][*] >= s+1    (uF = h(s))
//              and  flagsL1[bt][*] >= s       (vF = h1(s-1), 2-deep h1buf)
__global__ void __launch_bounds__(64, 1)
lstm_rec(const unsigned short* __restrict__ xseq,
         const unsigned short* __restrict__ U0p, const unsigned short* __restrict__ V0p,
         const unsigned short* __restrict__ U1p, const unsigned short* __restrict__ V1p,
         const float* __restrict__ bcat0, const float* __restrict__ bcat1,
         unsigned short* __restrict__ hbuf,   // [8][64][512] bf16
         unsigned short* __restrict__ h1buf,  // [2][64][512] bf16
         float* __restrict__ h1f,             // [64][512] fp32 final h1
         int* __restrict__ fl0,               // [4][32*FSTR] L0 flags
         int* __restrict__ fl1)               // [4][32*FSTR] L1 flags
{
  extern __shared__ unsigned short lds[];
  const int lane = threadIdx.x;
  const int wg = blockIdx.x;
  const bool isL1 = wg >= 128;
  const int wl = wg & 127;
  const int hb = wl >> 2, bt = wl & 3;
  const int l15 = lane & 15, g4 = lane >> 4;
  const int batch = bt * 16 + l15;
  const int hid4 = hb * 16 + g4 * 4;
  const int KU = isL1 ? 512 : 256;

  // stage this WG's weight slice (A-fragment layout) into LDS, once
  {
    const unsigned short* Wu = isL1 ? U1p : U0p;
    const unsigned short* Wv = isL1 ? V1p : V0p;
    const int nu = KU * 64, nv = 512 * 64;
    const bf16x8* su = (const bf16x8*)(Wu + (size_t)hb * nu);
    bf16x8* d = (bf16x8*)lds;
    for (int i = lane; i < nu / 8; i += 64) d[i] = su[i];
    const bf16x8* sv = (const bf16x8*)(Wv + (size_t)hb * nv);
    bf16x8* d2 = (bf16x8*)(lds + nu);
    for (int i = lane; i < nv / 8; i += 64) d2[i] = sv[i];
  }

  // per-lane poll pointer + threshold offset (thr = step - off)
  const int* pollp = (lane < 32) ? (fl0 + bt * 32 * FSTR + lane * FSTR)
                                 : (fl1 + bt * 32 * FSTR + (lane - 32) * FSTR);
  const int throff = isL1 ? (lane < 32 ? -1 : 0) : (lane < 32 ? 0 : 7);
  int* myflag = (isL1 ? fl1 : fl0) + bt * 32 * FSTR + hb * FSTR;

  const float* bc = isL1 ? bcat1 : bcat0;
  const float4 bF = *(const float4*)(bc + 0 * 512 + hid4);
  const float4 bI = *(const float4*)(bc + 1 * 512 + hid4);
  const float4 bG = *(const float4*)(bc + 2 * 512 + hid4);
  const float4 bO = *(const float4*)(bc + 3 * 512 + hid4);
  float cst[4] = {1.f, 1.f, 1.f, 1.f};

#define GATE_EPILOGUE(hv)                                                      \
  float hv[4];                                                                 \
  {                                                                            \
    const float bfv[4] = {bF.x, bF.y, bF.z, bF.w};                             \
    const float biv[4] = {bI.x, bI.y, bI.z, bI.w};                             \
    const float bgv[4] = {bG.x, bG.y, bG.z, bG.w};                             \
    const float bov[4] = {bO.x, bO.y, bO.z, bO.w};                             \
    _Pragma("unroll") for (int r = 0; r < 4; ++r) {                            \
      float fg = 1.f / (1.f + __expf(-(acc[0][r] + bfv[r])));                  \
      float ig = 1.f / (1.f + __expf(-(acc[1][r] + biv[r])));                  \
      float e2 = __expf(2.f * (acc[2][r] + bgv[r]));                           \
      float gg = (e2 - 1.f) / (e2 + 1.f);                                      \
      float og = 1.f / (1.f + __expf(-(acc[3][r] + bov[r])));                  \
      float cn = fg * cst[r] + ig * gg;                                        \
      cst[r] = cn;                                                             \
      float e2c = __expf(2.f * cn);                                            \
      hv[r] = og * (e2c - 1.f) / (e2c + 1.f);                                  \
    }                                                                          \
  }

  if (!isL1) {
    // ---------------- layer 0 ----------------
    bf16x8 xr[8];
    {
      const unsigned short* xp = xseq + (size_t)batch * kE + g4 * 8;  // t=0
#pragma unroll
      for (int kc = 0; kc < 8; ++kc) xr[kc] = *(const bf16x8*)(xp + kc * 32);
    }
    for (int t = 0; t < kT; ++t) {
      pollgate(pollp, t - throff);  // also drains xr prefetch (vmcnt 0)
      bf16x8 vF[16];
      issue16_sc1(hbuf + (size_t)((t + 7) & 7) * kBH + batch * kH + g4 * 8, vF);
      f32x4 acc[4] = {{0, 0, 0, 0}, {0, 0, 0, 0}, {0, 0, 0, 0}, {0, 0, 0, 0}};
#pragma unroll
      for (int kc = 0; kc < 8; ++kc) {  // U-part (x) while vF in flight
        const unsigned short* ab = lds + kc * 2048 + lane * 8;
        acc[0] = mfma16(*(const bf16x8*)ab, xr[kc], acc[0]);
        acc[1] = mfma16(*(const bf16x8*)(ab + 512), xr[kc], acc[1]);
        acc[2] = mfma16(*(const bf16x8*)(ab + 1024), xr[kc], acc[2]);
        acc[3] = mfma16(*(const bf16x8*)(ab + 1536), xr[kc], acc[3]);
      }
      wait_frags16(vF);
#pragma unroll
      for (int kc = 0; kc < 16; ++kc) {  // V-part (h recurrent)
        const unsigned short* ab = lds + (8 + kc) * 2048 + lane * 8;
        acc[0] = mfma16(*(const bf16x8*)ab, vF[kc], acc[0]);
        acc[1] = mfma16(*(const bf16x8*)(ab + 512), vF[kc], acc[1]);
        acc[2] = mfma16(*(const bf16x8*)(ab + 1024), vF[kc], acc[2]);
        acc[3] = mfma16(*(const bf16x8*)(ab + 1536), vF[kc], acc[3]);
      }
      GATE_EPILOGUE(hv)
      unsigned int lo = (unsigned)f2bf(hv[0]) | ((unsigned)f2bf(hv[1]) << 16);
      unsigned int hi = (unsigned)f2bf(hv[2]) | ((unsigned)f2bf(hv[3]) << 16);
      int32x2 pk = {(int)lo, (int)hi};
      store_dwordx2_sc1(hbuf + (size_t)(t & 7) * kBH + batch * kH + hid4, pk);
      if (t + 1 < kT) {  // prefetch next x; stays in flight across flag store
        const unsigned short* xp =
            xseq + ((size_t)(t + 1) * kB + batch) * kE + g4 * 8;
#pragma unroll
        for (int kc = 0; kc < 8; ++kc) xr[kc] = *(const bf16x8*)(xp + kc * 32);
        asm volatile("s_waitcnt vmcnt(8)" ::: "memory");  // h-store acked only
      } else {
        asm volatile("s_waitcnt vmcnt(0)" ::: "memory");
      }
      if (lane == 0) store_int_sc1(myflag, t + 1);
    }
  } else {
    // ---------------- layer 1 ----------------
    for (int s = 0; s < kT; ++s) {
      pollgate(pollp, s - throff);
      bf16x8 uF[16], vF[16];
      issue16_sc1(hbuf + (size_t)(s & 7) * kBH + batch * kH + g4 * 8, uF);
      issue16_sc1(h1buf + (size_t)((s + 1) & 1) * kBH + batch * kH + g4 * 8, vF);
      wait_frags16(uF);
      wait_frags16(vF);
      f32x4 acc[4] = {{0, 0, 0, 0}, {0, 0, 0, 0}, {0, 0, 0, 0}, {0, 0, 0, 0}};
#pragma unroll
      for (int kc = 0; kc < 16; ++kc) {  // U-part (h(s))
        const unsigned short* ab = lds + kc * 2048 + lane * 8;
        acc[0] = mfma16(*(const bf16x8*)ab, uF[kc], acc[0]);
        acc[1] = mfma16(*(const bf16x8*)(ab + 512), uF[kc], acc[1]);
        acc[2] = mfma16(*(const bf16x8*)(ab + 1024), uF[kc], acc[2]);
        acc[3] = mfma16(*(const bf16x8*)(ab + 1536), uF[kc], acc[3]);
      }
#pragma unroll
      for (int kc = 0; kc < 16; ++kc) {  // V-part (h1(s-1))
        const unsigned short* ab = lds + (16 + kc) * 2048 + lane * 8;
        acc[0] = mfma16(*(const bf16x8*)ab, vF[kc], acc[0]);
        acc[1] = mfma16(*(const bf16x8*)(ab + 512), vF[kc], acc[1]);
        acc[2] = mfma16(*(const bf16x8*)(ab + 1024), vF[kc], acc[2]);
        acc[3] = mfma16(*(const bf16x8*)(ab + 1536), vF[kc], acc[3]);
      }
      GATE_EPILOGUE(hv)
      if (s == kT - 1) {
        f32x4 hq = {hv[0], hv[1], hv[2], hv[3]};
        *(f32x4*)(h1f + (size_t)batch * kH + hid4) = hq;  // kernel-end flush
      } else {
        unsigned int lo = (unsigned)f2bf(hv[0]) | ((unsigned)f2bf(hv[1]) << 16);
        unsigned int hi = (unsigned)f2bf(hv[2]) | ((unsigned)f2bf(hv[3]) << 16);
        int32x2 pk = {(int)lo, (int)hi};
        store_dwordx2_sc1(h1buf + (size_t)(s & 1) * kBH + batch * kH + hid4, pk);
      }
      asm volatile("s_waitcnt vmcnt(0)" ::: "memory");
      if (lane == 0) store_int_sc1(myflag, s + 1);
    }
  }
#undef GATE_EPILOGUE
}

// out[b][v] = 2*sum_k h1[b][k]*Wout[k][v] + bout[v]; 32 batches per block
__global__ void head(const float* __restrict__ h1f, const float* __restrict__ Wout,
                     const float* __restrict__ bout, float* __restrict__ out) {
  extern __shared__ float hs[];  // [32][512]
  const int v = blockIdx.x * 256 + threadIdx.x;
  const int half = blockIdx.y;
  for (int i = threadIdx.x; i < 32 * kH; i += 256) hs[i] = h1f[half * 32 * kH + i];
  __syncthreads();
  float acc[32];
#pragma unroll
  for (int r = 0; r < 32; ++r) acc[r] = 0.f;
  for (int k = 0; k < kH; k += 4) {
    float w0 = Wout[(size_t)k * kV + v];
    float w1 = Wout[(size_t)(k + 1) * kV + v];
    float w2 = Wout[(size_t)(k + 2) * kV + v];
    float w3 = Wout[(size_t)(k + 3) * kV + v];
#pragma unroll
    for (int r = 0; r < 32; ++r) {
      float4 h4 = *(const float4*)&hs[r * kH + k];
      acc[r] += h4.x * w0 + h4.y * w1 + h4.z * w2 + h4.w * w3;
    }
  }
  float bv = bout[v];
#pragma unroll
  for (int r = 0; r < 32; ++r)
    out[(size_t)(half * 32 + r) * kV + v] = 2.f * acc[r] + bv;
}

extern "C" void kernel_launch(void* const* d_in, const int* in_sizes, int n_in,
                              void* d_out, int out_size, void* d_ws, size_t ws_size,
                              hipStream_t stream) {
  const int*   X     = (const int*)d_in[0];
  const float* emb   = (const float*)d_in[1];
  const float* U_f   = (const float*)d_in[2];
  const float* V_f   = (const float*)d_in[3];
  const float* b_f   = (const float*)d_in[4];
  const float* U_i   = (const float*)d_in[5];
  const float* V_i   = (const float*)d_in[6];
  const float* b_i   = (const float*)d_in[7];
  const float* U_g   = (const float*)d_in[8];
  const float* V_g   = (const float*)d_in[9];
  const float* b_g   = (const float*)d_in[10];
  const float* U_o   = (const float*)d_in[11];
  const float* U_f1  = (const float*)d_in[12];
  const float* V_f1  = (const float*)d_in[13];
  const float* b_f1  = (const float*)d_in[14];
  const float* U_i1  = (const float*)d_in[15];
  const float* V_i1  = (const float*)d_in[16];
  const float* b_i1  = (const float*)d_in[17];
  const float* U_g1  = (const float*)d_in[18];
  const float* V_g1  = (const float*)d_in[19];
  const float* b_g1  = (const float*)d_in[20];
  const float* U_o1  = (const float*)d_in[21];
  const float* V_o1  = (const float*)d_in[22];
  const float* b_o1  = (const float*)d_in[23];
  const float* W_out = (const float*)d_in[24];
  const float* b_out = (const float*)d_in[25];

  char* ws = (char*)d_ws;
  auto alloc = [&](size_t bytes) -> char* {
    char* p = ws;
    ws += (bytes + 255) & ~(size_t)255;
    return p;
  };
  unsigned short* U0p   = (unsigned short*)alloc((size_t)kE * 2048 * 2);
  unsigned short* V0p   = (unsigned short*)alloc((size_t)kH * 2048 * 2);
  unsigned short* U1p   = (unsigned short*)alloc((size_t)kH * 2048 * 2);
  unsigned short* V1p   = (unsigned short*)alloc((size_t)kH * 2048 * 2);
  unsigned short* xseq  = (unsigned short*)alloc((size_t)kT * kB * kE * 2);
  unsigned short* hbuf  = (unsigned short*)alloc((size_t)8 * kBH * 2);
  unsigned short* h1buf = (unsigned short*)alloc((size_t)2 * kBH * 2);
  float* h1f   = (float*)alloc((size_t)kBH * 4);
  float* bcat0 = (float*)alloc(4 * 512 * 4);
  float* bcat1 = (float*)alloc(4 * 512 * 4);
  int*   fl0   = (int*)alloc(4 * 32 * FSTR * 4);
  int*   fl1   = (int*)alloc(4 * 32 * FSTR * 4);

  // weight packing (layer0 o-gate uses V_o1 and b_o1 — reference quirk)
  pack_w<<<(kE * 2048 + 255) / 256, 256, 0, stream>>>(U_f, U_i, U_g, U_o, U0p, kE);
  pack_w<<<(kH * 2048 + 255) / 256, 256, 0, stream>>>(V_f, V_i, V_g, V_o1, V0p, kH);
  pack_w<<<(kH * 2048 + 255) / 256, 256, 0, stream>>>(U_f1, U_i1, U_g1, U_o1, U1p, kH);
  pack_w<<<(kH * 2048 + 255) / 256, 256, 0, stream>>>(V_f1, V_i1, V_g1, V_o1, V1p, kH);
  gather_x<<<(kT * kB * (kE / 8) + 255) / 256, 256, 0, stream>>>(X, emb, xseq);
  init_state<<<(8 * kBH + 255) / 256, 256, 0, stream>>>(
      hbuf, h1buf, bcat0, bcat1, fl0, fl1,
      b_f, b_i, b_g, b_o1, b_f1, b_i1, b_g1);

  (void)hipFuncSetAttribute((const void*)lstm_rec,
                            hipFuncAttributeMaxDynamicSharedMemorySize, 131072);
  void* args[] = {
      (void*)&xseq, (void*)&U0p, (void*)&V0p, (void*)&U1p, (void*)&V1p,
      (void*)&bcat0, (void*)&bcat1, (void*)&hbuf, (void*)&h1buf,
      (void*)&h1f, (void*)&fl0, (void*)&fl1};
  (void)hipLaunchCooperativeKernel((const void*)lstm_rec, dim3(256), dim3(64),
                                   args, 131072, stream);

  head<<<dim3(kV / 256, 2), 256, 65536, stream>>>(h1f, W_out, b_out, (float*)d_out);
}

// Round 14
// 2485.062 us; speedup vs baseline: 4.9625x; 1.0643x over previous
//
#include <hip/hip_runtime.h>
#include <hip/hip_bf16.h>

typedef __attribute__((ext_vector_type(8))) short bf16x8;
typedef __attribute__((ext_vector_type(4))) float f32x4;
typedef __attribute__((ext_vector_type(2))) int int32x2;

constexpr int kB = 64;      // batch
constexpr int kT = 512;     // time steps
constexpr int kE = 256;     // embedding
constexpr int kH = 512;     // hidden
constexpr int kV = 32000;   // vocab
constexpr int kBH = kB * kH;
constexpr int FSTR = 16;    // flag stride (ints) = 64B padding

static __device__ __forceinline__ unsigned short f2bf(float x) {
  __hip_bfloat16 h = __float2bfloat16(x);
  return __builtin_bit_cast(unsigned short, h);
}

static __device__ __forceinline__ f32x4 mfma16(bf16x8 a, bf16x8 b, f32x4 c) {
  return __builtin_amdgcn_mfma_f32_16x16x32_bf16(a, b, c, 0, 0, 0);
}

// issue 16 dwordx4 sc1 loads (64B stride), NO wait — overlap with compute.
static __device__ __forceinline__ void issue16_sc1(const unsigned short* p, bf16x8* a) {
  asm volatile(
      "global_load_dwordx4 %0, %16, off sc1\n\t"
      "global_load_dwordx4 %1, %16, off offset:64 sc1\n\t"
      "global_load_dwordx4 %2, %16, off offset:128 sc1\n\t"
      "global_load_dwordx4 %3, %16, off offset:192 sc1\n\t"
      "global_load_dwordx4 %4, %16, off offset:256 sc1\n\t"
      "global_load_dwordx4 %5, %16, off offset:320 sc1\n\t"
      "global_load_dwordx4 %6, %16, off offset:384 sc1\n\t"
      "global_load_dwordx4 %7, %16, off offset:448 sc1\n\t"
      "global_load_dwordx4 %8, %16, off offset:512 sc1\n\t"
      "global_load_dwordx4 %9, %16, off offset:576 sc1\n\t"
      "global_load_dwordx4 %10, %16, off offset:640 sc1\n\t"
      "global_load_dwordx4 %11, %16, off offset:704 sc1\n\t"
      "global_load_dwordx4 %12, %16, off offset:768 sc1\n\t"
      "global_load_dwordx4 %13, %16, off offset:832 sc1\n\t"
      "global_load_dwordx4 %14, %16, off offset:896 sc1\n\t"
      "global_load_dwordx4 %15, %16, off offset:960 sc1"
      : "=&v"(a[0]), "=&v"(a[1]), "=&v"(a[2]), "=&v"(a[3]),
        "=&v"(a[4]), "=&v"(a[5]), "=&v"(a[6]), "=&v"(a[7]),
        "=&v"(a[8]), "=&v"(a[9]), "=&v"(a[10]), "=&v"(a[11]),
        "=&v"(a[12]), "=&v"(a[13]), "=&v"(a[14]), "=&v"(a[15])
      : "v"(p));
}

// tied vmcnt(0) on 16 frags (rule-#18 safe: consumers data-dep on this asm)
static __device__ __forceinline__ void wait_frags16(bf16x8* a) {
  asm volatile("s_waitcnt vmcnt(0)"
               : "+v"(a[0]), "+v"(a[1]), "+v"(a[2]), "+v"(a[3]),
                 "+v"(a[4]), "+v"(a[5]), "+v"(a[6]), "+v"(a[7]),
                 "+v"(a[8]), "+v"(a[9]), "+v"(a[10]), "+v"(a[11]),
                 "+v"(a[12]), "+v"(a[13]), "+v"(a[14]), "+v"(a[15])
               :
               : "memory");
}

// tied vmcnt(16) on 16 frags: with 32 loads outstanding, the oldest 16 (these)
// are complete; the other 16 stay in flight.
static __device__ __forceinline__ void wait_frags16_vm16(bf16x8* a) {
  asm volatile("s_waitcnt vmcnt(16)"
               : "+v"(a[0]), "+v"(a[1]), "+v"(a[2]), "+v"(a[3]),
                 "+v"(a[4]), "+v"(a[5]), "+v"(a[6]), "+v"(a[7]),
                 "+v"(a[8]), "+v"(a[9]), "+v"(a[10]), "+v"(a[11]),
                 "+v"(a[12]), "+v"(a[13]), "+v"(a[14]), "+v"(a[15])
               :
               : "memory");
}

// tied vmcnt(8) on 8 frags: with 16 loads outstanding, oldest 8 complete.
static __device__ __forceinline__ void wait_frags8_vm8(bf16x8* a) {
  asm volatile("s_waitcnt vmcnt(8)"
               : "+v"(a[0]), "+v"(a[1]), "+v"(a[2]), "+v"(a[3]),
                 "+v"(a[4]), "+v"(a[5]), "+v"(a[6]), "+v"(a[7])
               :
               : "memory");
}

// tied vmcnt(0) on 8 frags
static __device__ __forceinline__ void wait_frags8(bf16x8* a) {
  asm volatile("s_waitcnt vmcnt(0)"
               : "+v"(a[0]), "+v"(a[1]), "+v"(a[2]), "+v"(a[3]),
                 "+v"(a[4]), "+v"(a[5]), "+v"(a[6]), "+v"(a[7])
               :
               : "memory");
}

static __device__ __forceinline__ void store_dwordx2_sc1(unsigned short* p, int32x2 v) {
  asm volatile("global_store_dwordx2 %0, %1, off sc1" ::"v"(p), "v"(v) : "memory");
}

static __device__ __forceinline__ void store_int_sc1(int* p, int v) {
  asm volatile("global_store_dword %0, %1, off sc1" ::"v"(p), "v"(v) : "memory");
}

// spin until (per-lane) *p >= thr for all 64 lanes; 1 dword sc1 load/lane/iter.
static __device__ __forceinline__ void pollgate(const int* p, int thr) {
  while (true) {
    int v;
    asm volatile("global_load_dword %0, %1, off sc1\n\ts_waitcnt vmcnt(0)"
                 : "=&v"(v)
                 : "v"(p)
                 : "memory");
    if (__all(v >= thr)) break;
  }
}

// Pack weights into A-fragment slices: P[hb][kc][gate][lane][j]
//   = src_gate[(kc*32 + (lane>>4)*8 + j) * kH + hb*16 + (lane&15)]
__global__ void pack_w(const float* __restrict__ s0, const float* __restrict__ s1,
                       const float* __restrict__ s2, const float* __restrict__ s3,
                       unsigned short* __restrict__ dst, int K) {
  int o = blockIdx.x * 256 + threadIdx.x;
  if (o >= K * 2048) return;
  int j = o & 7;
  int lane = (o >> 3) & 63;
  int gate = (o >> 9) & 3;
  int r2 = o >> 11;
  int kc = r2 % (K / 32);
  int hb = r2 / (K / 32);
  int k = kc * 32 + (lane >> 4) * 8 + j;
  int hid = hb * 16 + (lane & 15);
  const float* s = (gate == 0) ? s0 : (gate == 1) ? s1 : (gate == 2) ? s2 : s3;
  dst[o] = f2bf(s[(size_t)k * kH + hid]);
}

// xseq[t][b][e] = bf16(emb[X[b][t]][e])
__global__ void gather_x(const int* __restrict__ X, const float* __restrict__ emb,
                         unsigned short* __restrict__ xseq) {
  int o = blockIdx.x * 256 + threadIdx.x;
  if (o >= kT * kB * (kE / 8)) return;
  int e8 = o & 31;
  int b = (o >> 5) & 63;
  int t = o >> 11;
  int tok = X[b * kT + t];
  const float* src = emb + (size_t)tok * kE + e8 * 8;
  unsigned short tmp[8];
#pragma unroll
  for (int j = 0; j < 8; ++j) tmp[j] = f2bf(src[j]);
  unsigned short* dst = xseq + ((size_t)t * kB + b) * kE + e8 * 8;
#pragma unroll
  for (int j = 0; j < 8; ++j) dst[j] = tmp[j];
}

// init states to ones; planar bias arrays [4][512]; zero flags
__global__ void init_state(unsigned short* hbuf, unsigned short* h1buf,
                           float* bcat0, float* bcat1, int* fl0, int* fl1,
                           const float* b_f, const float* b_i, const float* b_g,
                           const float* b_o1,
                           const float* b_f1, const float* b_i1, const float* b_g1) {
  int i = blockIdx.x * 256 + threadIdx.x;
  if (i < 8 * kBH) hbuf[i] = 0x3F80u;  // bf16 1.0
  if (i < 2 * kBH) h1buf[i] = 0x3F80u;
  if (i < 512) {
    bcat0[i] = b_f[i];  bcat0[512 + i] = b_i[i];
    bcat0[1024 + i] = b_g[i];  bcat0[1536 + i] = b_o1[i];
    bcat1[i] = b_f1[i]; bcat1[512 + i] = b_i1[i];
    bcat1[1024 + i] = b_g1[i]; bcat1[1536 + i] = b_o1[i];
  }
  if (i < 4 * 32 * FSTR) { fl0[i] = 0; fl1[i] = 0; }
}

// Persistent recurrence: 256 WGs x 64 threads (1 wave each, 1 per CU).
// WGs [0,128): layer0 (h).  WGs [128,256): layer1 (h1).
// wl = wg&127; hb = wl>>2 (hidden block), bt = wl&3 (batch group of 16).
// Point-to-point flags along true dependencies, per bt-group (R6-proven):
//   L0 step t: fl0[bt][*] >= t (vF = h(t-1)); fl1[bt][*] >= t-7 (slot reuse)
//   L1 step s: fl0[bt][*] >= s+1 (uF = h(s)); fl1[bt][*] >= s (vF = h1(s-1))
__global__ void __launch_bounds__(64, 1)
lstm_rec(const unsigned short* __restrict__ xseq,
         const unsigned short* __restrict__ U0p, const unsigned short* __restrict__ V0p,
         const unsigned short* __restrict__ U1p, const unsigned short* __restrict__ V1p,
         const float* __restrict__ bcat0, const float* __restrict__ bcat1,
         unsigned short* __restrict__ hbuf,   // [8][64][512] bf16
         unsigned short* __restrict__ h1buf,  // [2][64][512] bf16
         float* __restrict__ h1f,             // [64][512] fp32 final h1
         int* __restrict__ fl0,               // [4][32*FSTR] L0 flags
         int* __restrict__ fl1)               // [4][32*FSTR] L1 flags
{
  extern __shared__ unsigned short lds[];
  const int lane = threadIdx.x;
  const int wg = blockIdx.x;
  const bool isL1 = wg >= 128;
  const int wl = wg & 127;
  const int hb = wl >> 2, bt = wl & 3;
  const int l15 = lane & 15, g4 = lane >> 4;
  const int batch = bt * 16 + l15;
  const int hid4 = hb * 16 + g4 * 4;
  const int KU = isL1 ? 512 : 256;

  // stage this WG's weight slice (A-fragment layout) into LDS, once
  {
    const unsigned short* Wu = isL1 ? U1p : U0p;
    const unsigned short* Wv = isL1 ? V1p : V0p;
    const int nu = KU * 64, nv = 512 * 64;
    const bf16x8* su = (const bf16x8*)(Wu + (size_t)hb * nu);
    bf16x8* d = (bf16x8*)lds;
    for (int i = lane; i < nu / 8; i += 64) d[i] = su[i];
    const bf16x8* sv = (const bf16x8*)(Wv + (size_t)hb * nv);
    bf16x8* d2 = (bf16x8*)(lds + nu);
    for (int i = lane; i < nv / 8; i += 64) d2[i] = sv[i];
  }

  // per-lane poll pointer + threshold offset (thr = step - off)
  const int* pollp = (lane < 32) ? (fl0 + bt * 32 * FSTR + lane * FSTR)
                                 : (fl1 + bt * 32 * FSTR + (lane - 32) * FSTR);
  const int throff = isL1 ? (lane < 32 ? -1 : 0) : (lane < 32 ? 0 : 7);
  int* myflag = (isL1 ? fl1 : fl0) + bt * 32 * FSTR + hb * FSTR;

  const float* bc = isL1 ? bcat1 : bcat0;
  const float4 bF = *(const float4*)(bc + 0 * 512 + hid4);
  const float4 bI = *(const float4*)(bc + 1 * 512 + hid4);
  const float4 bG = *(const float4*)(bc + 2 * 512 + hid4);
  const float4 bO = *(const float4*)(bc + 3 * 512 + hid4);
  float cst[4] = {1.f, 1.f, 1.f, 1.f};

#define GATE_EPILOGUE(hv)                                                      \
  float hv[4];                                                                 \
  {                                                                            \
    const float bfv[4] = {bF.x, bF.y, bF.z, bF.w};                             \
    const float biv[4] = {bI.x, bI.y, bI.z, bI.w};                             \
    const float bgv[4] = {bG.x, bG.y, bG.z, bG.w};                             \
    const float bov[4] = {bO.x, bO.y, bO.z, bO.w};                             \
    _Pragma("unroll") for (int r = 0; r < 4; ++r) {                            \
      float fg = 1.f / (1.f + __expf(-(acc[0][r] + bfv[r])));                  \
      float ig = 1.f / (1.f + __expf(-(acc[1][r] + biv[r])));                  \
      float e2 = __expf(2.f * (acc[2][r] + bgv[r]));                           \
      float gg = (e2 - 1.f) / (e2 + 1.f);                                      \
      float og = 1.f / (1.f + __expf(-(acc[3][r] + bov[r])));                  \
      float cn = fg * cst[r] + ig * gg;                                        \
      cst[r] = cn;                                                             \
      float e2c = __expf(2.f * cn);                                            \
      hv[r] = og * (e2c - 1.f) / (e2c + 1.f);                                  \
    }                                                                          \
  }

  if (!isL1) {
    // ================= layer 0 =================
    bf16x8 xr[8];
    {
      const unsigned short* xp = xseq + (size_t)batch * kE + g4 * 8;  // t=0
#pragma unroll
      for (int kc = 0; kc < 8; ++kc) xr[kc] = *(const bf16x8*)(xp + kc * 32);
    }
    for (int t = 0; t < kT; ++t) {
      pollgate(pollp, t - throff);  // also drains xr prefetch (vmcnt 0)
      bf16x8 vF[16];
      issue16_sc1(hbuf + (size_t)((t + 7) & 7) * kBH + batch * kH + g4 * 8, vF);
      f32x4 acc[4] = {{0, 0, 0, 0}, {0, 0, 0, 0}, {0, 0, 0, 0}, {0, 0, 0, 0}};
#pragma unroll
      for (int kc = 0; kc < 8; ++kc) {  // U-part (x) while vF in flight
        const unsigned short* ab = lds + kc * 2048 + lane * 8;
        acc[0] = mfma16(*(const bf16x8*)ab, xr[kc], acc[0]);
        acc[1] = mfma16(*(const bf16x8*)(ab + 512), xr[kc], acc[1]);
        acc[2] = mfma16(*(const bf16x8*)(ab + 1024), xr[kc], acc[2]);
        acc[3] = mfma16(*(const bf16x8*)(ab + 1536), xr[kc], acc[3]);
      }
      wait_frags8_vm8(vF);  // first 8 V-chunks complete; last 8 still flying
#pragma unroll
      for (int kc = 0; kc < 8; ++kc) {  // V-part (h recurrent) kc 0..7
        const unsigned short* ab = lds + (8 + kc) * 2048 + lane * 8;
        acc[0] = mfma16(*(const bf16x8*)ab, vF[kc], acc[0]);
        acc[1] = mfma16(*(const bf16x8*)(ab + 512), vF[kc], acc[1]);
        acc[2] = mfma16(*(const bf16x8*)(ab + 1024), vF[kc], acc[2]);
        acc[3] = mfma16(*(const bf16x8*)(ab + 1536), vF[kc], acc[3]);
      }
      wait_frags8(vF + 8);
#pragma unroll
      for (int kc = 8; kc < 16; ++kc) {  // V-part kc 8..15
        const unsigned short* ab = lds + (8 + kc) * 2048 + lane * 8;
        acc[0] = mfma16(*(const bf16x8*)ab, vF[kc], acc[0]);
        acc[1] = mfma16(*(const bf16x8*)(ab + 512), vF[kc], acc[1]);
        acc[2] = mfma16(*(const bf16x8*)(ab + 1024), vF[kc], acc[2]);
        acc[3] = mfma16(*(const bf16x8*)(ab + 1536), vF[kc], acc[3]);
      }
      GATE_EPILOGUE(hv)
      unsigned int lo = (unsigned)f2bf(hv[0]) | ((unsigned)f2bf(hv[1]) << 16);
      unsigned int hi = (unsigned)f2bf(hv[2]) | ((unsigned)f2bf(hv[3]) << 16);
      int32x2 pk = {(int)lo, (int)hi};
      store_dwordx2_sc1(hbuf + (size_t)(t & 7) * kBH + batch * kH + hid4, pk);
      if (t + 1 < kT) {  // prefetch next x; stays in flight across flag store
        const unsigned short* xp =
            xseq + ((size_t)(t + 1) * kB + batch) * kE + g4 * 8;
#pragma unroll
        for (int kc = 0; kc < 8; ++kc) xr[kc] = *(const bf16x8*)(xp + kc * 32);
        asm volatile("s_waitcnt vmcnt(8)" ::: "memory");  // h-store acked only
      } else {
        asm volatile("s_waitcnt vmcnt(0)" ::: "memory");
      }
      if (lane == 0) store_int_sc1(myflag, t + 1);
    }
  } else {
    // ================= layer 1 =================
    for (int s = 0; s < kT; ++s) {
      pollgate(pollp, s - throff);
      bf16x8 uF[16], vF[16];
      issue16_sc1(hbuf + (size_t)(s & 7) * kBH + batch * kH + g4 * 8, uF);
      issue16_sc1(h1buf + (size_t)((s + 1) & 1) * kBH + batch * kH + g4 * 8, vF);
      f32x4 acc[4] = {{0, 0, 0, 0}, {0, 0, 0, 0}, {0, 0, 0, 0}, {0, 0, 0, 0}};
      wait_frags16_vm16(uF);  // uF (oldest 16) done; vF still in flight
#pragma unroll
      for (int kc = 0; kc < 16; ++kc) {  // U-part (h(s)) overlaps vF RTT
        const unsigned short* ab = lds + kc * 2048 + lane * 8;
        acc[0] = mfma16(*(const bf16x8*)ab, uF[kc], acc[0]);
        acc[1] = mfma16(*(const bf16x8*)(ab + 512), uF[kc], acc[1]);
        acc[2] = mfma16(*(const bf16x8*)(ab + 1024), uF[kc], acc[2]);
        acc[3] = mfma16(*(const bf16x8*)(ab + 1536), uF[kc], acc[3]);
      }
      wait_frags16(vF);
#pragma unroll
      for (int kc = 0; kc < 16; ++kc) {  // V-part (h1(s-1))
        const unsigned short* ab = lds + (16 + kc) * 2048 + lane * 8;
        acc[0] = mfma16(*(const bf16x8*)ab, vF[kc], acc[0]);
        acc[1] = mfma16(*(const bf16x8*)(ab + 512), vF[kc], acc[1]);
        acc[2] = mfma16(*(const bf16x8*)(ab + 1024), vF[kc], acc[2]);
        acc[3] = mfma16(*(const bf16x8*)(ab + 1536), vF[kc], acc[3]);
      }
      GATE_EPILOGUE(hv)
      if (s == kT - 1) {
        f32x4 hq = {hv[0], hv[1], hv[2], hv[3]};
        *(f32x4*)(h1f + (size_t)batch * kH + hid4) = hq;  // kernel-end flush
      } else {
        unsigned int lo = (unsigned)f2bf(hv[0]) | ((unsigned)f2bf(hv[1]) << 16);
        unsigned int hi = (unsigned)f2bf(hv[2]) | ((unsigned)f2bf(hv[3]) << 16);
        int32x2 pk = {(int)lo, (int)hi};
        store_dwordx2_sc1(h1buf + (size_t)(s & 1) * kBH + batch * kH + hid4, pk);
      }
      asm volatile("s_waitcnt vmcnt(0)" ::: "memory");
      if (lane == 0) store_int_sc1(myflag, s + 1);
    }
  }
#undef GATE_EPILOGUE
}

// out[b][v] = 2*sum_k h1[b][k]*Wout[k][v] + bout[v]; 32 batches per block
__global__ void head(const float* __restrict__ h1f, const float* __restrict__ Wout,
                     const float* __restrict__ bout, float* __restrict__ out) {
  extern __shared__ float hs[];  // [32][512]
  const int v = blockIdx.x * 256 + threadIdx.x;
  const int half = blockIdx.y;
  for (int i = threadIdx.x; i < 32 * kH; i += 256) hs[i] = h1f[half * 32 * kH + i];
  __syncthreads();
  float acc[32];
#pragma unroll
  for (int r = 0; r < 32; ++r) acc[r] = 0.f;
  for (int k = 0; k < kH; k += 4) {
    float w0 = Wout[(size_t)k * kV + v];
    float w1 = Wout[(size_t)(k + 1) * kV + v];
    float w2 = Wout[(size_t)(k + 2) * kV + v];
    float w3 = Wout[(size_t)(k + 3) * kV + v];
#pragma unroll
    for (int r = 0; r < 32; ++r) {
      float4 h4 = *(const float4*)&hs[r * kH + k];
      acc[r] += h4.x * w0 + h4.y * w1 + h4.z * w2 + h4.w * w3;
    }
  }
  float bv = bout[v];
#pragma unroll
  for (int r = 0; r < 32; ++r)
    out[(size_t)(half * 32 + r) * kV + v] = 2.f * acc[r] + bv;
}

extern "C" void kernel_launch(void* const* d_in, const int* in_sizes, int n_in,
                              void* d_out, int out_size, void* d_ws, size_t ws_size,
                              hipStream_t stream) {
  const int*   X     = (const int*)d_in[0];
  const float* emb   = (const float*)d_in[1];
  const float* U_f   = (const float*)d_in[2];
  const float* V_f   = (const float*)d_in[3];
  const float* b_f   = (const float*)d_in[4];
  const float* U_i   = (const float*)d_in[5];
  const float* V_i   = (const float*)d_in[6];
  const float* b_i   = (const float*)d_in[7];
  const float* U_g   = (const float*)d_in[8];
  const float* V_g   = (const float*)d_in[9];
  const float* b_g   = (const float*)d_in[10];
  const float* U_o   = (const float*)d_in[11];
  const float* U_f1  = (const float*)d_in[12];
  const float* V_f1  = (const float*)d_in[13];
  const float* b_f1  = (const float*)d_in[14];
  const float* U_i1  = (const float*)d_in[15];
  const float* V_i1  = (const float*)d_in[16];
  const float* b_i1  = (const float*)d_in[17];
  const float* U_g1  = (const float*)d_in[18];
  const float* V_g1  = (const float*)d_in[19];
  const float* b_g1  = (const float*)d_in[20];
  const float* U_o1  = (const float*)d_in[21];
  const float* V_o1  = (const float*)d_in[22];
  const float* b_o1  = (const float*)d_in[23];
  const float* W_out = (const float*)d_in[24];
  const float* b_out = (const float*)d_in[25];

  char* ws = (char*)d_ws;
  auto alloc = [&](size_t bytes) -> char* {
    char* p = ws;
    ws += (bytes + 255) & ~(size_t)255;
    return p;
  };
  unsigned short* U0p   = (unsigned short*)alloc((size_t)kE * 2048 * 2);
  unsigned short* V0p   = (unsigned short*)alloc((size_t)kH * 2048 * 2);
  unsigned short* U1p   = (unsigned short*)alloc((size_t)kH * 2048 * 2);
  unsigned short* V1p   = (unsigned short*)alloc((size_t)kH * 2048 * 2);
  unsigned short* xseq  = (unsigned short*)alloc((size_t)kT * kB * kE * 2);
  unsigned short* hbuf  = (unsigned short*)alloc((size_t)8 * kBH * 2);
  unsigned short* h1buf = (unsigned short*)alloc((size_t)2 * kBH * 2);
  float* h1f   = (float*)alloc((size_t)kBH * 4);
  float* bcat0 = (float*)alloc(4 * 512 * 4);
  float* bcat1 = (float*)alloc(4 * 512 * 4);
  int* fl0     = (int*)alloc(4 * 32 * FSTR * 4);
  int* fl1     = (int*)alloc(4 * 32 * FSTR * 4);

  // weight packing (layer0 o-gate uses V_o1 and b_o1 — reference quirk)
  pack_w<<<(kE * 2048 + 255) / 256, 256, 0, stream>>>(U_f, U_i, U_g, U_o, U0p, kE);
  pack_w<<<(kH * 2048 + 255) / 256, 256, 0, stream>>>(V_f, V_i, V_g, V_o1, V0p, kH);
  pack_w<<<(kH * 2048 + 255) / 256, 256, 0, stream>>>(U_f1, U_i1, U_g1, U_o1, U1p, kH);
  pack_w<<<(kH * 2048 + 255) / 256, 256, 0, stream>>>(V_f1, V_i1, V_g1, V_o1, V1p, kH);
  gather_x<<<(kT * kB * (kE / 8) + 255) / 256, 256, 0, stream>>>(X, emb, xseq);
  init_state<<<(8 * kBH + 255) / 256, 256, 0, stream>>>(
      hbuf, h1buf, bcat0, bcat1, fl0, fl1,
      b_f, b_i, b_g, b_o1, b_f1, b_i1, b_g1);

  (void)hipFuncSetAttribute((const void*)lstm_rec,
                            hipFuncAttributeMaxDynamicSharedMemorySize, 131072);
  void* args[] = {
      (void*)&xseq, (void*)&U0p, (void*)&V0p, (void*)&U1p, (void*)&V1p,
      (void*)&bcat0, (void*)&bcat1, (void*)&hbuf, (void*)&h1buf,
      (void*)&h1f, (void*)&fl0, (void*)&fl1};
  (void)hipLaunchCooperativeKernel((const void*)lstm_rec, dim3(256), dim3(64),
                                   args, 131072, stream);

  head<<<dim3(kV / 256, 2), 256, 65536, stream>>>(h1f, W_out, b_out, (float*)d_out);
}